// Round 4
// baseline (75.824 us; speedup 1.0000x reference)
//
#include <hip/hip_runtime.h>

// MPDNN SchNet-style MPNN, 5-dispatch pipeline.
// R2 measured: cooperative grid.sync costs ~120us/barrier on gfx950 (XCD L2
// writeback + cross-die polling) -> multi-dispatch chain is the right shape.
// R3 calibration: graph launch overhead ~3us/kernel; kernels sum ~45us.
// R4: ILP round — 4-way message unroll (nbr lists padded to x8), unroll-8
// matvec loops, folded reduction stages (fewer barriers), uint4 staging,
// prep folded to 1024 blocks.
//  - Wf(d) -> 4096-row fp32 lookup table (2 MB, L2-resident)
//  - compact neighbor lists (d<6, ~23% dense), entry = j | (table_row<<7)
//  - h fp32 (residual) + producer-packed bf16 (message staging)
//  - conv1 reads emb[species] directly; conv3 fuses NodePool + pre_i/pre_j
//  - c_aniso.sum(j) pushed through @We2

#define LN2F 0.69314718055994531f

__device__ __forceinline__ float sspf(float x) {          // softplus(x) - ln2, stable
  float e = __expf(-fabsf(x));
  return fmaxf(x, 0.0f) + __logf(1.0f + e) - LN2F;
}
__device__ __forceinline__ unsigned int f2bf(float x) {   // fp32 -> bf16 bits (RNE)
  unsigned int u = __float_as_uint(x);
  return (u + 0x7fffu + ((u >> 16) & 1u)) >> 16;
}
__device__ __forceinline__ float bflo(unsigned int u) { return __uint_as_float(u << 16); }
__device__ __forceinline__ float bfhi(unsigned int u) { return __uint_as_float(u & 0xffff0000u); }

// ---------------------------------------------------------------------------
// prep: 1024 blocks x 256. Each block: neighbor lists for 2 nodes + 4 table rows.
// ---------------------------------------------------------------------------
__global__ __launch_bounds__(256) void prep_kernel(
    const float* __restrict__ coords,
    const float* __restrict__ Wc1, const float* __restrict__ bc1,
    const float* __restrict__ Wc2, const float* __restrict__ bc2,
    float* __restrict__ table,
    unsigned int* __restrict__ ent, int* __restrict__ cnt) {
  __shared__ int wc[4];
  __shared__ float rbf[4][32];
  __shared__ float hid[4][128];
  int t = threadIdx.x;
  int blk = blockIdx.x;

  // --- A: neighbor lists for nodes blk*2, blk*2+1 ---
  {
    int node = blk * 2 + (t >> 7);
    int j = t & 127;
    int b = node >> 7, i = node & 127;
    const float* cb = coords + (b << 7) * 3;
    float dx = cb[i*3+0] - cb[j*3+0];
    float dy = cb[i*3+1] - cb[j*3+1];
    float dz = cb[i*3+2] - cb[j*3+2];
    float d  = sqrtf(dx*dx + dy*dy + dz*dz);
    bool valid = (d < 6.0f) && (j != i);
    int k = 4096;                                   // 4096 = zero row (pad)
    if (valid) { k = (int)(d * (4096.0f/6.0f)); if (k > 4095) k = 4095; }
    unsigned long long bal = __ballot(valid);
    int lane = t & 63, w = t >> 6;
    if (lane == 0) wc[w] = (int)__popcll(bal);
    __syncthreads();
    int ii = t >> 7;
    int nn = wc[2*ii] + wc[2*ii+1];
    int base = ((w & 1) ? wc[w-1] : 0) + (int)__popcll(bal & ((1ull << lane) - 1ull));
    if (valid) ent[node*128 + base] = (unsigned int)(j | (k << 7));
    int nnp = (nn + 7) & ~7;                        // pad to x8 for 4-way unroll
    if (nnp > 128) nnp = 128;                       // nn<=127 -> nnp<=128
    if (j >= nn && j < nnp) ent[node*128 + j] = (4096u << 7);
    if (j == 0) cnt[node] = nn | (nnp << 16);
  }
  // --- B: table rows blk*4 .. blk*4+3 ---
  {
    int r0 = blk * 4;
    if (t < 128) {
      int tt = t >> 5, kk = t & 31;
      float d = (float)(r0 + tt) * (6.0f/4096.0f) + 0.5f * (6.0f/4096.0f);
      float mu = 0.5f + (float)kk * (5.5f/31.0f);
      float z = d - mu;
      rbf[tt][kk] = __expf(-8.0f * z * z);          // 1/(2*0.25^2)=8
    }
    __syncthreads();
    int f = t & 127, sub = t >> 7;                  // sub in 0..1 -> 2 rows each
    int ra = sub*2, rb = ra + 1;
    float s0 = bc1[f], s1 = s0;
#pragma unroll 8
    for (int kk = 0; kk < 32; kk++) {
      float wv = Wc1[kk*128 + f];
      s0 += rbf[ra][kk]*wv; s1 += rbf[rb][kk]*wv;
    }
    hid[ra][f] = sspf(s0); hid[rb][f] = sspf(s1);
    __syncthreads();
    float o0 = bc2[f], o1 = o0;
#pragma unroll 8
    for (int g = 0; g < 128; g++) {
      float wv = Wc2[g*128 + f];
      o0 += hid[ra][g]*wv; o1 += hid[rb][g]*wv;
    }
    table[(r0+ra)*128 + f] = o0;
    table[(r0+rb)*128 + f] = o1;
    if (blk == 0 && t < 128) table[4096*128 + t] = 0.0f;
  }
}

// ---------------------------------------------------------------------------
// conv: one block = 4 nodes. message (table-gather) + update net.
// SRC_EMB: h_in is emb[species] on the fly (conv 1).
// LAST:    skip h stores; fuse NodePool (c_iso) + pre_i/pre_j (conv 3).
// ---------------------------------------------------------------------------
template<bool SRC_EMB, bool LAST>
__global__ __launch_bounds__(512) void conv_t(
    const float* __restrict__ h_in, const unsigned int* __restrict__ hbf_in,
    float* __restrict__ h_out, unsigned int* __restrict__ hbf_out,
    const int* __restrict__ species, const float* __restrict__ emb,
    const float* __restrict__ table, const unsigned int* __restrict__ ent,
    const int* __restrict__ cnt,
    const float* __restrict__ Wu1, const float* __restrict__ bu1,
    const float* __restrict__ Wu2, const float* __restrict__ bu2,
    const float* __restrict__ Wp1, const float* __restrict__ bp1,
    const float* __restrict__ Wp2, const float* __restrict__ bp2,
    const float* __restrict__ Wei, const float* __restrict__ Wej,
    float* __restrict__ pre_i, unsigned int* __restrict__ prejbf,
    float* __restrict__ out) {
  __shared__ unsigned int hsh[8192];        // h[b] as bf16x2, 32 KB
  __shared__ unsigned int ent_s[4][128];
  __shared__ float mred[8][128];
  __shared__ float scr[4][128];             // scratch (pool phase)
  __shared__ float red[4][4][128];
  __shared__ float u1_s[4][128];
  __shared__ int nn_s[4];
  int t = threadIdx.x;
  int node0 = blockIdx.x * 4;
  int b = blockIdx.x >> 5;

  if constexpr (SRC_EMB) {
    const int* spb = species + (b << 7);
    const float4* emb4 = (const float4*)emb;
    for (int c = 0; c < 8; c++) {
      int idx = c*512 + t;
      int j = idx >> 5, f4 = idx & 31;      // 32 float4 per 128-f row
      float4 v = emb4[spb[j]*32 + f4];
      uint2 pk;
      pk.x = (f2bf(v.y) << 16) | f2bf(v.x);
      pk.y = (f2bf(v.w) << 16) | f2bf(v.z);
      ((uint2*)hsh)[j*32 + f4] = pk;
    }
  } else {
    const uint4* hb4 = (const uint4*)(hbf_in + b * 8192);
    uint4* hsh4 = (uint4*)hsh;
    for (int c = 0; c < 4; c++) hsh4[c*512 + t] = hb4[c*512 + t];
  }
  { int ii = t >> 7, f = t & 127;
    ent_s[ii][f] = ent[(node0 + ii)*128 + f]; }
  if (t < 4) nn_s[t] = cnt[node0 + t];
  __syncthreads();

  // --- message: 2 waves/node by parity, 4 entries per iteration in flight ---
  int w = t >> 6, lane = t & 63;
  int ii = w >> 1, par = w & 1;
  int nnp = nn_s[ii] >> 16;                 // padded count (multiple of 8)
  float a0 = 0.f, a1 = 0.f, b0 = 0.f, b1 = 0.f;
  float c0 = 0.f, c1 = 0.f, d0 = 0.f, d1 = 0.f;
  for (int e = par; e < nnp; e += 8) {
    unsigned int u0 = ent_s[ii][e],     u1 = ent_s[ii][e + 2];
    unsigned int u2 = ent_s[ii][e + 4], u3 = ent_s[ii][e + 6];
    float2 t0 = *(const float2*)(table + (u0 >> 7)*128 + 2*lane);
    float2 t1 = *(const float2*)(table + (u1 >> 7)*128 + 2*lane);
    float2 t2 = *(const float2*)(table + (u2 >> 7)*128 + 2*lane);
    float2 t3 = *(const float2*)(table + (u3 >> 7)*128 + 2*lane);
    unsigned int h0 = hsh[(u0 & 127)*64 + lane];
    unsigned int h1 = hsh[(u1 & 127)*64 + lane];
    unsigned int h2 = hsh[(u2 & 127)*64 + lane];
    unsigned int h3 = hsh[(u3 & 127)*64 + lane];
    a0 += t0.x * bflo(h0); a1 += t0.y * bfhi(h0);
    b0 += t1.x * bflo(h1); b1 += t1.y * bfhi(h1);
    c0 += t2.x * bflo(h2); c1 += t2.y * bfhi(h2);
    d0 += t3.x * bflo(h3); d1 += t3.y * bfhi(h3);
  }
  a0 += b0 + c0 + d0; a1 += b1 + c1 + d1;
  *(float2*)&mred[w][2*lane] = make_float2(a0, a1);
  __syncthreads();

  // --- update net (m folded from mred pairs), 4 rows batched per weight load ---
  int g = t & 127, q = t >> 7;
  {
    float p0=0,p1=0,p2=0,p3=0;
#pragma unroll 8
    for (int f = q*32; f < q*32 + 32; f++) {
      float wv = Wu1[f*128 + g];
      p0 += (mred[0][f]+mred[1][f])*wv; p1 += (mred[2][f]+mred[3][f])*wv;
      p2 += (mred[4][f]+mred[5][f])*wv; p3 += (mred[6][f]+mred[7][f])*wv;
    }
    red[q][0][g]=p0; red[q][1][g]=p1; red[q][2][g]=p2; red[q][3][g]=p3;
  }
  __syncthreads();
  { int i2 = t >> 7, gg = t & 127;
    u1_s[i2][gg] = sspf(red[0][i2][gg]+red[1][i2][gg]+red[2][i2][gg]+red[3][i2][gg] + bu1[gg]); }
  __syncthreads();
  {
    float p0=0,p1=0,p2=0,p3=0;
#pragma unroll 8
    for (int f = q*32; f < q*32 + 32; f++) {
      float wv = Wu2[f*128 + g];
      p0 += u1_s[0][f]*wv; p1 += u1_s[1][f]*wv; p2 += u1_s[2][f]*wv; p3 += u1_s[3][f]*wv;
    }
    red[q][0][g]=p0; red[q][1][g]=p1; red[q][2][g]=p2; red[q][3][g]=p3;
  }
  __syncthreads();
  { int i2 = t >> 7, o = t & 127;
    int node = node0 + i2;
    float delta = red[0][i2][o]+red[1][i2][o]+red[2][i2][o]+red[3][i2][o] + bu2[o];
    float base;
    if constexpr (SRC_EMB) base = emb[species[node]*128 + o];
    else                   base = h_in[node*128 + o];
    float hf = base + delta;
    if constexpr (!LAST) {
      h_out[node*128 + o] = hf;
      unsigned int lo = f2bf(hf);
      unsigned int hi = (unsigned int)__shfl_xor((int)lo, 1);
      if ((o & 1) == 0) hbf_out[node*64 + (o >> 1)] = lo | (hi << 16);
    } else {
      u1_s[i2][o] = hf;                     // keep h for pools
    }
  }
  if constexpr (LAST) {
    __syncthreads();
    float (*hs)[128]     = u1_s;
    float (*redp)[4][64] = reinterpret_cast<float (*)[4][64]>(red);
    float (*us)[64]      = reinterpret_cast<float (*)[64]>(scr);
    int gp = t & 63, qp = t >> 6;           // qp 0..7 -> 16-wide f segment
    float p0=0,p1=0,p2=0,p3=0;
#pragma unroll 8
    for (int f = qp*16; f < qp*16 + 16; f++) {
      float wv = Wp1[f*64 + gp];
      p0 += hs[0][f]*wv; p1 += hs[1][f]*wv; p2 += hs[2][f]*wv; p3 += hs[3][f]*wv;
    }
    redp[qp][0][gp]=p0; redp[qp][1][gp]=p1; redp[qp][2][gp]=p2; redp[qp][3][gp]=p3;
    __syncthreads();
    if (t < 256) {
      int i4 = t >> 6, gg = t & 63;
      float s = bp1[gg];
#pragma unroll
      for (int q2 = 0; q2 < 8; q2++) s += redp[q2][i4][gg];
      us[i4][gg] = sspf(s);
    }
    __syncthreads();
    if (t < 32) {
      int i4 = t >> 3, o = t & 7;
      float v = bp2[o];
#pragma unroll 8
      for (int gg = 0; gg < 64; gg++) v += us[i4][gg] * Wp2[gg*8 + o];
      out[(node0 + i4)*8 + o] = v;
    }
    int o = t & 127, sel = (t >> 7) & 1, duo = t >> 8;
    const float* W = sel ? Wej : Wei;
    float q0 = 0.f, q1 = 0.f;
#pragma unroll 8
    for (int f = 0; f < 128; f++) {
      float wv = W[f*128 + o];
      q0 += hs[2*duo][f]*wv; q1 += hs[2*duo+1][f]*wv;
    }
    if (sel == 0) {
      pre_i[(node0 + 2*duo)*128 + o]     = q0;
      pre_i[(node0 + 2*duo + 1)*128 + o] = q1;
    } else {
      unsigned int l0 = f2bf(q0), l1 = f2bf(q1);
      unsigned int h0 = (unsigned int)__shfl_xor((int)l0, 1);
      unsigned int h1 = (unsigned int)__shfl_xor((int)l1, 1);
      if ((o & 1) == 0) {
        prejbf[(node0 + 2*duo)*64 + (o >> 1)]     = l0 | (h0 << 16);
        prejbf[(node0 + 2*duo + 1)*64 + (o >> 1)] = l1 | (h1 << 16);
      }
    }
  }
}

// ---------------------------------------------------------------------------
// edgepool: c_aniso_sum[node] = (sum_j ssp(pre_i+be1+pre_j)) @ We2 + be2*nn
// ---------------------------------------------------------------------------
__global__ __launch_bounds__(512) void edgepool_kernel(
    const float* __restrict__ pre_i, const unsigned int* __restrict__ prejbf,
    const unsigned int* __restrict__ ent, const int* __restrict__ cnt,
    const float* __restrict__ be1, const float* __restrict__ We2,
    const float* __restrict__ be2, float* __restrict__ out) {
  __shared__ unsigned int pjs[8192];        // pre_j[b] bf16x2, 32 KB
  __shared__ unsigned int ent_s[4][128];
  __shared__ float pis[4][128];
  __shared__ float sred[8][128];
  __shared__ float r2[4][8][16];
  __shared__ int nn_s[4];
  int t = threadIdx.x;
  int node0 = blockIdx.x * 4;
  int b = blockIdx.x >> 5;
  { const uint4* pjb4 = (const uint4*)(prejbf + b * 8192);
    uint4* pjs4 = (uint4*)pjs;
    for (int c = 0; c < 4; c++) pjs4[c*512 + t] = pjb4[c*512 + t]; }
  { int ii = t >> 7, f = t & 127;
    pis[ii][f] = pre_i[(node0 + ii)*128 + f] + be1[f];
    ent_s[ii][f] = ent[(node0 + ii)*128 + f]; }
  if (t < 4) nn_s[t] = cnt[node0 + t] & 0xffff;   // true neighbor count
  __syncthreads();
  int w = t >> 6, lane = t & 63;
  int ii = w >> 1, par = w & 1;
  float pia = pis[ii][2*lane];
  float pib = pis[ii][2*lane + 1];
  int nn = nn_s[ii];
  float a0 = 0.f, a1 = 0.f;
  for (int e = par; e < nn; e += 2) {
    unsigned int u = ent_s[ii][e];
    int j = u & 127;
    unsigned int hv = pjs[j*64 + lane];
    a0 += sspf(pia + bflo(hv));
    a1 += sspf(pib + bfhi(hv));
  }
  *(float2*)&sred[w][2*lane] = make_float2(a0, a1);
  __syncthreads();
  { int i2 = t >> 7, o = t & 15, seg = (t >> 4) & 7;
    float p = 0.f;
#pragma unroll
    for (int f = seg*16; f < seg*16 + 16; f++)
      p += (sred[2*i2][f] + sred[2*i2+1][f]) * We2[f*16 + o];
    r2[i2][seg][o] = p; }
  __syncthreads();
  if (t < 64) {
    int i2 = t >> 4, o = t & 15;
    float v = be2[o] * (float)nn_s[i2];
#pragma unroll
    for (int seg = 0; seg < 8; seg++) v += r2[i2][seg][o];
    out[(node0 + i2)*16 + o] = v;
  }
}

// ---------------------------------------------------------------------------
extern "C" void kernel_launch(void* const* d_in, const int* in_sizes, int n_in,
                              void* d_out, int out_size, void* d_ws, size_t ws_size,
                              hipStream_t stream) {
  const float* coords = (const float*)d_in[0];
  const int*   species= (const int*)  d_in[1];
  const float* emb    = (const float*)d_in[2];
  const float* Wc1    = (const float*)d_in[3];
  const float* bc1    = (const float*)d_in[4];
  const float* Wc2    = (const float*)d_in[5];
  const float* bc2    = (const float*)d_in[6];
  const float* Wu1    = (const float*)d_in[7];
  const float* bu1    = (const float*)d_in[8];
  const float* Wu2    = (const float*)d_in[9];
  const float* bu2    = (const float*)d_in[10];
  const float* Wp1    = (const float*)d_in[11];
  const float* bp1    = (const float*)d_in[12];
  const float* Wp2    = (const float*)d_in[13];
  const float* bp2    = (const float*)d_in[14];
  const float* Wei    = (const float*)d_in[15];
  const float* Wej    = (const float*)d_in[16];
  const float* be1    = (const float*)d_in[17];
  const float* We2    = (const float*)d_in[18];
  const float* be2    = (const float*)d_in[19];
  float* out = (float*)d_out;

  float* wsf = (float*)d_ws;
  float*        table  = wsf;                              //  524,416
  float*        h_a    = wsf + 524416;                     //  262,144
  float*        h_b    = wsf + 786560;                     //  262,144
  float*        pre_i  = wsf + 1048704;                    //  262,144
  unsigned int* hbf_a  = (unsigned int*)(wsf + 1310848);   //  131,072
  unsigned int* hbf_b  = (unsigned int*)(wsf + 1441920);   //  131,072
  unsigned int* prejbf = (unsigned int*)(wsf + 1572992);   //  131,072
  unsigned int* ent    = (unsigned int*)(wsf + 1704064);   //  262,144
  int*          cnt    = (int*)(wsf + 1966208);            //  2,048
  (void)in_sizes; (void)n_in; (void)out_size; (void)ws_size;

  prep_kernel<<<1024, 256, 0, stream>>>(coords, Wc1, bc1, Wc2, bc2, table, ent, cnt);
  conv_t<true, false><<<512, 512, 0, stream>>>(
      nullptr, nullptr, h_b, hbf_b, species, emb, table, ent, cnt,
      Wu1, bu1, Wu2, bu2,
      nullptr, nullptr, nullptr, nullptr, nullptr, nullptr, nullptr, nullptr, nullptr);
  conv_t<false, false><<<512, 512, 0, stream>>>(
      h_b, hbf_b, h_a, hbf_a, species, emb, table, ent, cnt,
      Wu1, bu1, Wu2, bu2,
      nullptr, nullptr, nullptr, nullptr, nullptr, nullptr, nullptr, nullptr, nullptr);
  conv_t<false, true><<<512, 512, 0, stream>>>(
      h_a, hbf_a, nullptr, nullptr, species, emb, table, ent, cnt,
      Wu1, bu1, Wu2, bu2,
      Wp1, bp1, Wp2, bp2, Wei, Wej, pre_i, prejbf, out);
  edgepool_kernel<<<512, 512, 0, stream>>>(pre_i, prejbf, ent, cnt, be1, We2, be2,
                                           out + 16384);
}

// Round 5
// 62.634 us; speedup vs baseline: 1.2106x; 1.2106x over previous
//
#include <hip/hip_runtime.h>

// MPDNN SchNet-style MPNN, 5-dispatch pipeline.
// R2 measured: cooperative grid.sync ~120us/barrier on gfx950 -> multi-dispatch.
// R3 (60.1us) proven base. R4 ILP round regressed (75.8): prep de-batching
// (2-row/thread table blocks) + forced unrolls. R5: revert conv/edgepool to R3
// exactly; prep table half -> 256 blocks x 16 rows (8-row batching, from R1).
//  - Wf(d) -> 4096-row fp32 lookup table (2 MB, L2-resident)
//  - compact neighbor lists (d<6, ~23% dense), entry = j | (table_row<<7)
//  - h fp32 (residual) + producer-packed bf16 (message staging)
//  - conv1 reads emb[species] directly; conv3 fuses NodePool + pre_i/pre_j
//  - c_aniso.sum(j) pushed through @We2

#define LN2F 0.69314718055994531f

__device__ __forceinline__ float sspf(float x) {          // softplus(x) - ln2, stable
  float e = __expf(-fabsf(x));
  return fmaxf(x, 0.0f) + __logf(1.0f + e) - LN2F;
}
__device__ __forceinline__ unsigned int f2bf(float x) {   // fp32 -> bf16 bits (RNE)
  unsigned int u = __float_as_uint(x);
  return (u + 0x7fffu + ((u >> 16) & 1u)) >> 16;
}
__device__ __forceinline__ float bflo(unsigned int u) { return __uint_as_float(u << 16); }
__device__ __forceinline__ float bfhi(unsigned int u) { return __uint_as_float(u & 0xffff0000u); }

// ---------------------------------------------------------------------------
// prep: blocks [0,1024): neighbor lists (2 nodes/block)
//       blocks [1024,1280): filter table, 16 d-samples/block (8-row batching)
// ---------------------------------------------------------------------------
__global__ __launch_bounds__(256) void prep_kernel(
    const float* __restrict__ coords,
    const float* __restrict__ Wc1, const float* __restrict__ bc1,
    const float* __restrict__ Wc2, const float* __restrict__ bc2,
    float* __restrict__ table,
    unsigned int* __restrict__ ent, int* __restrict__ cnt) {
  int t = threadIdx.x;
  if (blockIdx.x < 1024) {
    __shared__ int wc[4];
    int node = blockIdx.x * 2 + (t >> 7);
    int j = t & 127;
    int b = node >> 7, i = node & 127;
    const float* cb = coords + (b << 7) * 3;
    float dx = cb[i*3+0] - cb[j*3+0];
    float dy = cb[i*3+1] - cb[j*3+1];
    float dz = cb[i*3+2] - cb[j*3+2];
    float d  = sqrtf(dx*dx + dy*dy + dz*dz);
    bool valid = (d < 6.0f) && (j != i);
    int k = 4096;                                   // 4096 = zero row (pad)
    if (valid) { k = (int)(d * (4096.0f/6.0f)); if (k > 4095) k = 4095; }
    unsigned long long bal = __ballot(valid);
    int lane = t & 63, w = t >> 6;
    if (lane == 0) wc[w] = (int)__popcll(bal);
    __syncthreads();
    int ii = t >> 7;
    int nn = wc[2*ii] + wc[2*ii+1];
    int base = ((w & 1) ? wc[w-1] : 0) + (int)__popcll(bal & ((1ull << lane) - 1ull));
    if (valid) ent[node*128 + base] = (unsigned int)(j | (k << 7));
    int nnp = (nn + 3) & ~3;
    if (j >= nn && j < nnp) ent[node*128 + j] = (4096u << 7);
    if (j == 0) cnt[node] = nn | (nnp << 16);
  } else {
    __shared__ float rbf_all[16][32];
    __shared__ float hid_all[16][128];
    int tb = (int)blockIdx.x - 1024;                // 0..255
    int t0 = tb * 16;
    for (int idx = t; idx < 512; idx += 256) {
      int tt = idx >> 5, kk = idx & 31;
      float d = (float)(t0 + tt) * (6.0f/4096.0f) + 0.5f * (6.0f/4096.0f);
      float mu = 0.5f + (float)kk * (5.5f/31.0f);
      float z = d - mu;
      rbf_all[tt][kk] = __expf(-8.0f * z * z);      // 1/(2*0.25^2)=8
    }
    __syncthreads();
    int f = t & 127, sub = t >> 7;                  // sub handles rows sub*8..+7
    float s[8];
    float b1 = bc1[f];
#pragma unroll
    for (int r = 0; r < 8; r++) s[r] = b1;
    for (int kk = 0; kk < 32; kk++) {
      float wv = Wc1[kk*128 + f];
#pragma unroll
      for (int r = 0; r < 8; r++) s[r] += rbf_all[sub*8 + r][kk] * wv;
    }
#pragma unroll
    for (int r = 0; r < 8; r++) hid_all[sub*8 + r][f] = sspf(s[r]);
    __syncthreads();
    float o[8];
    float b2 = bc2[f];
#pragma unroll
    for (int r = 0; r < 8; r++) o[r] = b2;
    for (int g = 0; g < 128; g++) {
      float wv = Wc2[g*128 + f];
#pragma unroll
      for (int r = 0; r < 8; r++) o[r] += hid_all[sub*8 + r][g] * wv;
    }
#pragma unroll
    for (int r = 0; r < 8; r++) table[(t0 + sub*8 + r)*128 + f] = o[r];
    if (tb == 0 && t < 128) table[4096*128 + t] = 0.0f;
  }
}

// ---------------------------------------------------------------------------
// conv: one block = 4 nodes. message (table-gather) + update net.
// SRC_EMB: h_in is emb[species] computed on the fly (conv 1).
// LAST:    skip h stores; fuse NodePool (c_iso) + pre_i/pre_j (conv 3).
// ---------------------------------------------------------------------------
template<bool SRC_EMB, bool LAST>
__global__ __launch_bounds__(512) void conv_t(
    const float* __restrict__ h_in, const unsigned int* __restrict__ hbf_in,
    float* __restrict__ h_out, unsigned int* __restrict__ hbf_out,
    const int* __restrict__ species, const float* __restrict__ emb,
    const float* __restrict__ table, const unsigned int* __restrict__ ent,
    const int* __restrict__ cnt,
    const float* __restrict__ Wu1, const float* __restrict__ bu1,
    const float* __restrict__ Wu2, const float* __restrict__ bu2,
    const float* __restrict__ Wp1, const float* __restrict__ bp1,
    const float* __restrict__ Wp2, const float* __restrict__ bp2,
    const float* __restrict__ Wei, const float* __restrict__ Wej,
    float* __restrict__ pre_i, unsigned int* __restrict__ prejbf,
    float* __restrict__ out) {
  __shared__ unsigned int hsh[8192];        // h[b] as bf16x2, 32 KB
  __shared__ unsigned int ent_s[4][128];
  __shared__ float mred[8][128];
  __shared__ float m_s[4][128];
  __shared__ float red[4][4][128];
  __shared__ float u1_s[4][128];
  __shared__ int nn_s[4];
  int t = threadIdx.x;
  int node0 = blockIdx.x * 4;
  int b = blockIdx.x >> 5;

  if constexpr (SRC_EMB) {
    const int* spb = species + (b << 7);
    for (int c = 0; c < 16; c++) {
      int idx = c*512 + t;
      int j = idx >> 6, f2 = idx & 63;
      float2 v = *(const float2*)(emb + spb[j]*128 + 2*f2);
      hsh[idx] = (f2bf(v.y) << 16) | f2bf(v.x);
    }
  } else {
    const unsigned int* hb = hbf_in + b * 8192;
    for (int c = 0; c < 16; c++) hsh[c*512 + t] = hb[c*512 + t];
  }
  { int ii = t >> 7, f = t & 127;
    ent_s[ii][f] = ent[(node0 + ii)*128 + f]; }
  if (t < 4) nn_s[t] = cnt[node0 + t];
  __syncthreads();

  // --- message: wave pair strides the neighbor list, 2-way unrolled ---
  int w = t >> 6, lane = t & 63;
  int ii = w >> 1, par = w & 1;
  int nnp = nn_s[ii] >> 16;                 // padded count (multiple of 4)
  float a0 = 0.f, a1 = 0.f, c0 = 0.f, c1 = 0.f;
  for (int e = par; e + 2 < nnp; e += 4) {
    unsigned int u0 = ent_s[ii][e], u1 = ent_s[ii][e + 2];
    int j0 = u0 & 127, k0 = (int)(u0 >> 7);
    int j1 = u1 & 127, k1 = (int)(u1 >> 7);
    float2 t0 = *(const float2*)(table + k0*128 + 2*lane);
    float2 t1 = *(const float2*)(table + k1*128 + 2*lane);
    unsigned int h0 = hsh[j0*64 + lane];
    unsigned int h1 = hsh[j1*64 + lane];
    a0 += t0.x * bflo(h0); a1 += t0.y * bfhi(h0);
    c0 += t1.x * bflo(h1); c1 += t1.y * bfhi(h1);
  }
  a0 += c0; a1 += c1;
  *(float2*)&mred[w][2*lane] = make_float2(a0, a1);
  __syncthreads();
  { int i2 = t >> 7, f = t & 127;
    m_s[i2][f] = mred[2*i2][f] + mred[2*i2+1][f]; }
  __syncthreads();

  // --- update net, 4 rows batched per weight load ---
  int g = t & 127, q = t >> 7;
  {
    float p0=0,p1=0,p2=0,p3=0;
    for (int f = q*32; f < q*32 + 32; f++) {
      float wv = Wu1[f*128 + g];
      p0 += m_s[0][f]*wv; p1 += m_s[1][f]*wv; p2 += m_s[2][f]*wv; p3 += m_s[3][f]*wv;
    }
    red[q][0][g]=p0; red[q][1][g]=p1; red[q][2][g]=p2; red[q][3][g]=p3;
  }
  __syncthreads();
  { int i2 = t >> 7, gg = t & 127;
    u1_s[i2][gg] = sspf(red[0][i2][gg]+red[1][i2][gg]+red[2][i2][gg]+red[3][i2][gg] + bu1[gg]); }
  __syncthreads();
  {
    float p0=0,p1=0,p2=0,p3=0;
    for (int f = q*32; f < q*32 + 32; f++) {
      float wv = Wu2[f*128 + g];
      p0 += u1_s[0][f]*wv; p1 += u1_s[1][f]*wv; p2 += u1_s[2][f]*wv; p3 += u1_s[3][f]*wv;
    }
    red[q][0][g]=p0; red[q][1][g]=p1; red[q][2][g]=p2; red[q][3][g]=p3;
  }
  __syncthreads();
  { int i2 = t >> 7, o = t & 127;
    int node = node0 + i2;
    float delta = red[0][i2][o]+red[1][i2][o]+red[2][i2][o]+red[3][i2][o] + bu2[o];
    float base;
    if constexpr (SRC_EMB) base = emb[species[node]*128 + o];
    else                   base = h_in[node*128 + o];
    float hf = base + delta;
    if constexpr (!LAST) {
      h_out[node*128 + o] = hf;
      unsigned int lo = f2bf(hf);
      unsigned int hi = (unsigned int)__shfl_xor((int)lo, 1);
      if ((o & 1) == 0) hbf_out[node*64 + (o >> 1)] = lo | (hi << 16);
    } else {
      u1_s[i2][o] = hf;                     // u1 dead here; keep h for pools
    }
  }
  if constexpr (LAST) {
    __syncthreads();
    float (*hs)[128]     = u1_s;
    float (*redp)[4][64] = reinterpret_cast<float (*)[4][64]>(red);
    float (*us)[64]      = reinterpret_cast<float (*)[64]>(m_s);
    int gp = t & 63, qp = t >> 6;           // qp 0..7 -> 16-wide f segment
    float p0=0,p1=0,p2=0,p3=0;
    for (int f = qp*16; f < qp*16 + 16; f++) {
      float wv = Wp1[f*64 + gp];
      p0 += hs[0][f]*wv; p1 += hs[1][f]*wv; p2 += hs[2][f]*wv; p3 += hs[3][f]*wv;
    }
    redp[qp][0][gp]=p0; redp[qp][1][gp]=p1; redp[qp][2][gp]=p2; redp[qp][3][gp]=p3;
    __syncthreads();
    if (t < 256) {
      int i4 = t >> 6, gg = t & 63;
      float s = bp1[gg];
      for (int q2 = 0; q2 < 8; q2++) s += redp[q2][i4][gg];
      us[i4][gg] = sspf(s);
    }
    __syncthreads();
    if (t < 32) {
      int i4 = t >> 3, o = t & 7;
      float v = bp2[o];
      for (int gg = 0; gg < 64; gg++) v += us[i4][gg] * Wp2[gg*8 + o];
      out[(node0 + i4)*8 + o] = v;
    }
    int o = t & 127, sel = (t >> 7) & 1, duo = t >> 8;
    const float* W = sel ? Wej : Wei;
    float q0 = 0.f, q1 = 0.f;
    for (int f = 0; f < 128; f++) {
      float wv = W[f*128 + o];
      q0 += hs[2*duo][f]*wv; q1 += hs[2*duo+1][f]*wv;
    }
    if (sel == 0) {
      pre_i[(node0 + 2*duo)*128 + o]     = q0;
      pre_i[(node0 + 2*duo + 1)*128 + o] = q1;
    } else {
      unsigned int l0 = f2bf(q0), l1 = f2bf(q1);
      unsigned int h0 = (unsigned int)__shfl_xor((int)l0, 1);
      unsigned int h1 = (unsigned int)__shfl_xor((int)l1, 1);
      if ((o & 1) == 0) {
        prejbf[(node0 + 2*duo)*64 + (o >> 1)]     = l0 | (h0 << 16);
        prejbf[(node0 + 2*duo + 1)*64 + (o >> 1)] = l1 | (h1 << 16);
      }
    }
  }
}

// ---------------------------------------------------------------------------
// edgepool: c_aniso_sum[node] = (sum_j ssp(pre_i+be1+pre_j)) @ We2 + be2*nn
// ---------------------------------------------------------------------------
__global__ __launch_bounds__(512) void edgepool_kernel(
    const float* __restrict__ pre_i, const unsigned int* __restrict__ prejbf,
    const unsigned int* __restrict__ ent, const int* __restrict__ cnt,
    const float* __restrict__ be1, const float* __restrict__ We2,
    const float* __restrict__ be2, float* __restrict__ out) {
  __shared__ unsigned int pjs[8192];        // pre_j[b] bf16x2, 32 KB
  __shared__ unsigned int ent_s[4][128];
  __shared__ float pis[4][128];
  __shared__ float sred[8][128];
  __shared__ float s_s[4][128];
  __shared__ float r2[4][8][16];
  __shared__ int nn_s[4];
  int t = threadIdx.x;
  int node0 = blockIdx.x * 4;
  int b = blockIdx.x >> 5;
  const unsigned int* pjb = prejbf + b * 8192;
  for (int c = 0; c < 16; c++) pjs[c*512 + t] = pjb[c*512 + t];
  { int ii = t >> 7, f = t & 127;
    pis[ii][f] = pre_i[(node0 + ii)*128 + f] + be1[f];
    ent_s[ii][f] = ent[(node0 + ii)*128 + f]; }
  if (t < 4) nn_s[t] = cnt[node0 + t] & 0xffff;   // true neighbor count
  __syncthreads();
  int w = t >> 6, lane = t & 63;
  int ii = w >> 1, par = w & 1;
  float pia = pis[ii][2*lane];
  float pib = pis[ii][2*lane + 1];
  int nn = nn_s[ii];
  float a0 = 0.f, a1 = 0.f;
  for (int e = par; e < nn; e += 2) {
    unsigned int u = ent_s[ii][e];
    int j = u & 127;
    unsigned int hv = pjs[j*64 + lane];
    a0 += sspf(pia + bflo(hv));
    a1 += sspf(pib + bfhi(hv));
  }
  *(float2*)&sred[w][2*lane] = make_float2(a0, a1);
  __syncthreads();
  { int i2 = t >> 7, f = t & 127;
    s_s[i2][f] = sred[2*i2][f] + sred[2*i2+1][f]; }
  __syncthreads();
  { int i2 = t >> 7, o = t & 15, seg = (t >> 4) & 7;
    float p = 0.f;
    for (int f = seg*16; f < seg*16 + 16; f++) p += s_s[i2][f] * We2[f*16 + o];
    r2[i2][seg][o] = p; }
  __syncthreads();
  if (t < 64) {
    int i2 = t >> 4, o = t & 15;
    float v = be2[o] * (float)nn_s[i2];
    for (int seg = 0; seg < 8; seg++) v += r2[i2][seg][o];
    out[(node0 + i2)*16 + o] = v;
  }
}

// ---------------------------------------------------------------------------
extern "C" void kernel_launch(void* const* d_in, const int* in_sizes, int n_in,
                              void* d_out, int out_size, void* d_ws, size_t ws_size,
                              hipStream_t stream) {
  const float* coords = (const float*)d_in[0];
  const int*   species= (const int*)  d_in[1];
  const float* emb    = (const float*)d_in[2];
  const float* Wc1    = (const float*)d_in[3];
  const float* bc1    = (const float*)d_in[4];
  const float* Wc2    = (const float*)d_in[5];
  const float* bc2    = (const float*)d_in[6];
  const float* Wu1    = (const float*)d_in[7];
  const float* bu1    = (const float*)d_in[8];
  const float* Wu2    = (const float*)d_in[9];
  const float* bu2    = (const float*)d_in[10];
  const float* Wp1    = (const float*)d_in[11];
  const float* bp1    = (const float*)d_in[12];
  const float* Wp2    = (const float*)d_in[13];
  const float* bp2    = (const float*)d_in[14];
  const float* Wei    = (const float*)d_in[15];
  const float* Wej    = (const float*)d_in[16];
  const float* be1    = (const float*)d_in[17];
  const float* We2    = (const float*)d_in[18];
  const float* be2    = (const float*)d_in[19];
  float* out = (float*)d_out;

  float* wsf = (float*)d_ws;
  float*        table  = wsf;                              //  524,416
  float*        h_a    = wsf + 524416;                     //  262,144
  float*        h_b    = wsf + 786560;                     //  262,144
  float*        pre_i  = wsf + 1048704;                    //  262,144
  unsigned int* hbf_a  = (unsigned int*)(wsf + 1310848);   //  131,072
  unsigned int* hbf_b  = (unsigned int*)(wsf + 1441920);   //  131,072
  unsigned int* prejbf = (unsigned int*)(wsf + 1572992);   //  131,072
  unsigned int* ent    = (unsigned int*)(wsf + 1704064);   //  262,144
  int*          cnt    = (int*)(wsf + 1966208);            //  2,048
  (void)in_sizes; (void)n_in; (void)out_size; (void)ws_size;

  prep_kernel<<<1280, 256, 0, stream>>>(coords, Wc1, bc1, Wc2, bc2, table, ent, cnt);
  conv_t<true, false><<<512, 512, 0, stream>>>(
      nullptr, nullptr, h_b, hbf_b, species, emb, table, ent, cnt,
      Wu1, bu1, Wu2, bu2,
      nullptr, nullptr, nullptr, nullptr, nullptr, nullptr, nullptr, nullptr, nullptr);
  conv_t<false, false><<<512, 512, 0, stream>>>(
      h_b, hbf_b, h_a, hbf_a, species, emb, table, ent, cnt,
      Wu1, bu1, Wu2, bu2,
      nullptr, nullptr, nullptr, nullptr, nullptr, nullptr, nullptr, nullptr, nullptr);
  conv_t<false, true><<<512, 512, 0, stream>>>(
      h_a, hbf_a, nullptr, nullptr, species, emb, table, ent, cnt,
      Wu1, bu1, Wu2, bu2,
      Wp1, bp1, Wp2, bp2, Wei, Wej, pre_i, prejbf, out);
  edgepool_kernel<<<512, 512, 0, stream>>>(pre_i, prejbf, ent, cnt, be1, We2, be2,
                                           out + 16384);
}

// Round 6
// 57.091 us; speedup vs baseline: 1.3281x; 1.0971x over previous
//
#include <hip/hip_runtime.h>

// MPDNN SchNet-style MPNN, 5-dispatch pipeline.
// R2: cooperative grid.sync ~120us/barrier on gfx950 -> multi-dispatch chain.
// R3 (60.1us) anchor. R4 (75.8) regression = prep de-batching. R5 (62.6)
// fat-table null -> prep table is latency-bound; noise ~±2.5us.
// R6: prep reverted to exact R3; message gather 4-way in flight (pad x8);
// bf16-packed filter table (half gather bytes, 2MB->1MB footprint).
//  - Wf(d) -> 4096-row bf16 lookup table (1 MB, L2/L3-resident)
//  - compact neighbor lists (d<6, ~23% dense), entry = j | (table_row<<7)
//  - h fp32 (residual) + producer-packed bf16 (message staging)
//  - conv1 reads emb[species] directly; conv3 fuses NodePool + pre_i/pre_j
//  - c_aniso.sum(j) pushed through @We2

#define LN2F 0.69314718055994531f

__device__ __forceinline__ float sspf(float x) {          // softplus(x) - ln2, stable
  float e = __expf(-fabsf(x));
  return fmaxf(x, 0.0f) + __logf(1.0f + e) - LN2F;
}
__device__ __forceinline__ unsigned int f2bf(float x) {   // fp32 -> bf16 bits (RNE)
  unsigned int u = __float_as_uint(x);
  return (u + 0x7fffu + ((u >> 16) & 1u)) >> 16;
}
__device__ __forceinline__ float bflo(unsigned int u) { return __uint_as_float(u << 16); }
__device__ __forceinline__ float bfhi(unsigned int u) { return __uint_as_float(u & 0xffff0000u); }

// ---------------------------------------------------------------------------
// prep: blocks [0,1024): neighbor lists (2 nodes/block), pad to x8
//       blocks [1024,1536): filter table, 8 d-samples/block (4-row batching),
//                           packed to bf16x2 (64 uints/row)
// ---------------------------------------------------------------------------
__global__ __launch_bounds__(256) void prep_kernel(
    const float* __restrict__ coords,
    const float* __restrict__ Wc1, const float* __restrict__ bc1,
    const float* __restrict__ Wc2, const float* __restrict__ bc2,
    unsigned int* __restrict__ tb16,
    unsigned int* __restrict__ ent, int* __restrict__ cnt) {
  int t = threadIdx.x;
  if (blockIdx.x < 1024) {
    __shared__ int wc[4];
    int node = blockIdx.x * 2 + (t >> 7);
    int j = t & 127;
    int b = node >> 7, i = node & 127;
    const float* cb = coords + (b << 7) * 3;
    float dx = cb[i*3+0] - cb[j*3+0];
    float dy = cb[i*3+1] - cb[j*3+1];
    float dz = cb[i*3+2] - cb[j*3+2];
    float d  = sqrtf(dx*dx + dy*dy + dz*dz);
    bool valid = (d < 6.0f) && (j != i);
    int k = 4096;                                   // 4096 = zero row (pad)
    if (valid) { k = (int)(d * (4096.0f/6.0f)); if (k > 4095) k = 4095; }
    unsigned long long bal = __ballot(valid);
    int lane = t & 63, w = t >> 6;
    if (lane == 0) wc[w] = (int)__popcll(bal);
    __syncthreads();
    int ii = t >> 7;
    int nn = wc[2*ii] + wc[2*ii+1];
    int base = ((w & 1) ? wc[w-1] : 0) + (int)__popcll(bal & ((1ull << lane) - 1ull));
    if (valid) ent[node*128 + base] = (unsigned int)(j | (k << 7));
    int nnp = (nn + 7) & ~7;                        // pad to x8 for 4-way unroll
    if (nnp > 128) nnp = 128;                       // nn<=127 -> ok
    if (j >= nn && j < nnp) ent[node*128 + j] = (4096u << 7);
    if (j == 0) cnt[node] = nn | (nnp << 16);
  } else {
    __shared__ float rbf[8][32];
    __shared__ float hid[8][128];
    int tb = (int)blockIdx.x - 1024;                // 0..511
    int t0 = tb * 8;
    { int tt = t >> 5, kk = t & 31;                 // 256 threads = 8x32 exactly
      float d = (float)(t0 + tt) * (6.0f/4096.0f) + 0.5f * (6.0f/4096.0f);
      float mu = 0.5f + (float)kk * (5.5f/31.0f);
      float z = d - mu;
      rbf[tt][kk] = __expf(-8.0f * z * z); }        // 1/(2*0.25^2)=8
    __syncthreads();
    int f = t & 127, sub = t >> 7;                  // sub in 0..1 -> rows sub*4..+3
    float s0 = bc1[f], s1 = s0, s2 = s0, s3 = s0;
    int r0 = sub * 4;
    for (int kk = 0; kk < 32; kk++) {
      float wv = Wc1[kk*128 + f];
      s0 += rbf[r0+0][kk]*wv; s1 += rbf[r0+1][kk]*wv;
      s2 += rbf[r0+2][kk]*wv; s3 += rbf[r0+3][kk]*wv;
    }
    hid[r0+0][f] = sspf(s0); hid[r0+1][f] = sspf(s1);
    hid[r0+2][f] = sspf(s2); hid[r0+3][f] = sspf(s3);
    __syncthreads();
    float o0 = bc2[f], o1 = o0, o2 = o0, o3 = o0;
    for (int g = 0; g < 128; g++) {
      float wv = Wc2[g*128 + f];
      o0 += hid[r0+0][g]*wv; o1 += hid[r0+1][g]*wv;
      o2 += hid[r0+2][g]*wv; o3 += hid[r0+3][g]*wv;
    }
    // pack pairs of columns to bf16x2 (even f writes word f>>1)
    unsigned int l0 = f2bf(o0), l1 = f2bf(o1), l2 = f2bf(o2), l3 = f2bf(o3);
    unsigned int p0 = (unsigned int)__shfl_xor((int)l0, 1);
    unsigned int p1 = (unsigned int)__shfl_xor((int)l1, 1);
    unsigned int p2 = (unsigned int)__shfl_xor((int)l2, 1);
    unsigned int p3 = (unsigned int)__shfl_xor((int)l3, 1);
    if ((f & 1) == 0) {
      int fw = f >> 1;
      tb16[(t0+r0+0)*64 + fw] = l0 | (p0 << 16);
      tb16[(t0+r0+1)*64 + fw] = l1 | (p1 << 16);
      tb16[(t0+r0+2)*64 + fw] = l2 | (p2 << 16);
      tb16[(t0+r0+3)*64 + fw] = l3 | (p3 << 16);
    }
    if (tb == 0 && t < 64) tb16[4096*64 + t] = 0u;  // zero pad row
  }
}

// ---------------------------------------------------------------------------
// conv: one block = 4 nodes. message (bf16-table gather, 4 in flight) + update net.
// SRC_EMB: h_in is emb[species] computed on the fly (conv 1).
// LAST:    skip h stores; fuse NodePool (c_iso) + pre_i/pre_j (conv 3).
// ---------------------------------------------------------------------------
template<bool SRC_EMB, bool LAST>
__global__ __launch_bounds__(512) void conv_t(
    const float* __restrict__ h_in, const unsigned int* __restrict__ hbf_in,
    float* __restrict__ h_out, unsigned int* __restrict__ hbf_out,
    const int* __restrict__ species, const float* __restrict__ emb,
    const unsigned int* __restrict__ tb16, const unsigned int* __restrict__ ent,
    const int* __restrict__ cnt,
    const float* __restrict__ Wu1, const float* __restrict__ bu1,
    const float* __restrict__ Wu2, const float* __restrict__ bu2,
    const float* __restrict__ Wp1, const float* __restrict__ bp1,
    const float* __restrict__ Wp2, const float* __restrict__ bp2,
    const float* __restrict__ Wei, const float* __restrict__ Wej,
    float* __restrict__ pre_i, unsigned int* __restrict__ prejbf,
    float* __restrict__ out) {
  __shared__ unsigned int hsh[8192];        // h[b] as bf16x2, 32 KB
  __shared__ unsigned int ent_s[4][128];
  __shared__ float mred[8][128];
  __shared__ float m_s[4][128];
  __shared__ float red[4][4][128];
  __shared__ float u1_s[4][128];
  __shared__ int nn_s[4];
  int t = threadIdx.x;
  int node0 = blockIdx.x * 4;
  int b = blockIdx.x >> 5;

  if constexpr (SRC_EMB) {
    const int* spb = species + (b << 7);
    for (int c = 0; c < 16; c++) {
      int idx = c*512 + t;
      int j = idx >> 6, f2 = idx & 63;
      float2 v = *(const float2*)(emb + spb[j]*128 + 2*f2);
      hsh[idx] = (f2bf(v.y) << 16) | f2bf(v.x);
    }
  } else {
    const unsigned int* hb = hbf_in + b * 8192;
    for (int c = 0; c < 16; c++) hsh[c*512 + t] = hb[c*512 + t];
  }
  { int ii = t >> 7, f = t & 127;
    ent_s[ii][f] = ent[(node0 + ii)*128 + f]; }
  if (t < 4) nn_s[t] = cnt[node0 + t];
  __syncthreads();

  // --- message: wave pair by parity, 4 gathers in flight ---
  int w = t >> 6, lane = t & 63;
  int ii = w >> 1, par = w & 1;
  int nnp = nn_s[ii] >> 16;                 // padded count (multiple of 8)
  float a0 = 0.f, a1 = 0.f, b0 = 0.f, b1 = 0.f;
  float c0 = 0.f, c1 = 0.f, d0 = 0.f, d1 = 0.f;
  for (int e = par; e < nnp; e += 8) {
    unsigned int u0 = ent_s[ii][e],     u1 = ent_s[ii][e + 2];
    unsigned int u2 = ent_s[ii][e + 4], u3 = ent_s[ii][e + 6];
    unsigned int t0 = tb16[(u0 >> 7)*64 + lane];
    unsigned int t1 = tb16[(u1 >> 7)*64 + lane];
    unsigned int t2 = tb16[(u2 >> 7)*64 + lane];
    unsigned int t3 = tb16[(u3 >> 7)*64 + lane];
    unsigned int h0 = hsh[(u0 & 127)*64 + lane];
    unsigned int h1 = hsh[(u1 & 127)*64 + lane];
    unsigned int h2 = hsh[(u2 & 127)*64 + lane];
    unsigned int h3 = hsh[(u3 & 127)*64 + lane];
    a0 += bflo(t0) * bflo(h0); a1 += bfhi(t0) * bfhi(h0);
    b0 += bflo(t1) * bflo(h1); b1 += bfhi(t1) * bfhi(h1);
    c0 += bflo(t2) * bflo(h2); c1 += bfhi(t2) * bfhi(h2);
    d0 += bflo(t3) * bflo(h3); d1 += bfhi(t3) * bfhi(h3);
  }
  a0 += b0 + c0 + d0; a1 += b1 + c1 + d1;
  *(float2*)&mred[w][2*lane] = make_float2(a0, a1);
  __syncthreads();
  { int i2 = t >> 7, f = t & 127;
    m_s[i2][f] = mred[2*i2][f] + mred[2*i2+1][f]; }
  __syncthreads();

  // --- update net, 4 rows batched per weight load ---
  int g = t & 127, q = t >> 7;
  {
    float p0=0,p1=0,p2=0,p3=0;
    for (int f = q*32; f < q*32 + 32; f++) {
      float wv = Wu1[f*128 + g];
      p0 += m_s[0][f]*wv; p1 += m_s[1][f]*wv; p2 += m_s[2][f]*wv; p3 += m_s[3][f]*wv;
    }
    red[q][0][g]=p0; red[q][1][g]=p1; red[q][2][g]=p2; red[q][3][g]=p3;
  }
  __syncthreads();
  { int i2 = t >> 7, gg = t & 127;
    u1_s[i2][gg] = sspf(red[0][i2][gg]+red[1][i2][gg]+red[2][i2][gg]+red[3][i2][gg] + bu1[gg]); }
  __syncthreads();
  {
    float p0=0,p1=0,p2=0,p3=0;
    for (int f = q*32; f < q*32 + 32; f++) {
      float wv = Wu2[f*128 + g];
      p0 += u1_s[0][f]*wv; p1 += u1_s[1][f]*wv; p2 += u1_s[2][f]*wv; p3 += u1_s[3][f]*wv;
    }
    red[q][0][g]=p0; red[q][1][g]=p1; red[q][2][g]=p2; red[q][3][g]=p3;
  }
  __syncthreads();
  { int i2 = t >> 7, o = t & 127;
    int node = node0 + i2;
    float delta = red[0][i2][o]+red[1][i2][o]+red[2][i2][o]+red[3][i2][o] + bu2[o];
    float base;
    if constexpr (SRC_EMB) base = emb[species[node]*128 + o];
    else                   base = h_in[node*128 + o];
    float hf = base + delta;
    if constexpr (!LAST) {
      h_out[node*128 + o] = hf;
      unsigned int lo = f2bf(hf);
      unsigned int hi = (unsigned int)__shfl_xor((int)lo, 1);
      if ((o & 1) == 0) hbf_out[node*64 + (o >> 1)] = lo | (hi << 16);
    } else {
      u1_s[i2][o] = hf;                     // u1 dead here; keep h for pools
    }
  }
  if constexpr (LAST) {
    __syncthreads();
    float (*hs)[128]     = u1_s;
    float (*redp)[4][64] = reinterpret_cast<float (*)[4][64]>(red);
    float (*us)[64]      = reinterpret_cast<float (*)[64]>(m_s);
    int gp = t & 63, qp = t >> 6;           // qp 0..7 -> 16-wide f segment
    float p0=0,p1=0,p2=0,p3=0;
    for (int f = qp*16; f < qp*16 + 16; f++) {
      float wv = Wp1[f*64 + gp];
      p0 += hs[0][f]*wv; p1 += hs[1][f]*wv; p2 += hs[2][f]*wv; p3 += hs[3][f]*wv;
    }
    redp[qp][0][gp]=p0; redp[qp][1][gp]=p1; redp[qp][2][gp]=p2; redp[qp][3][gp]=p3;
    __syncthreads();
    if (t < 256) {
      int i4 = t >> 6, gg = t & 63;
      float s = bp1[gg];
      for (int q2 = 0; q2 < 8; q2++) s += redp[q2][i4][gg];
      us[i4][gg] = sspf(s);
    }
    __syncthreads();
    if (t < 32) {
      int i4 = t >> 3, o = t & 7;
      float v = bp2[o];
      for (int gg = 0; gg < 64; gg++) v += us[i4][gg] * Wp2[gg*8 + o];
      out[(node0 + i4)*8 + o] = v;
    }
    int o = t & 127, sel = (t >> 7) & 1, duo = t >> 8;
    const float* W = sel ? Wej : Wei;
    float q0 = 0.f, q1 = 0.f;
    for (int f = 0; f < 128; f++) {
      float wv = W[f*128 + o];
      q0 += hs[2*duo][f]*wv; q1 += hs[2*duo+1][f]*wv;
    }
    if (sel == 0) {
      pre_i[(node0 + 2*duo)*128 + o]     = q0;
      pre_i[(node0 + 2*duo + 1)*128 + o] = q1;
    } else {
      unsigned int l0 = f2bf(q0), l1 = f2bf(q1);
      unsigned int h0 = (unsigned int)__shfl_xor((int)l0, 1);
      unsigned int h1 = (unsigned int)__shfl_xor((int)l1, 1);
      if ((o & 1) == 0) {
        prejbf[(node0 + 2*duo)*64 + (o >> 1)]     = l0 | (h0 << 16);
        prejbf[(node0 + 2*duo + 1)*64 + (o >> 1)] = l1 | (h1 << 16);
      }
    }
  }
}

// ---------------------------------------------------------------------------
// edgepool: c_aniso_sum[node] = (sum_j ssp(pre_i+be1+pre_j)) @ We2 + be2*nn
// ---------------------------------------------------------------------------
__global__ __launch_bounds__(512) void edgepool_kernel(
    const float* __restrict__ pre_i, const unsigned int* __restrict__ prejbf,
    const unsigned int* __restrict__ ent, const int* __restrict__ cnt,
    const float* __restrict__ be1, const float* __restrict__ We2,
    const float* __restrict__ be2, float* __restrict__ out) {
  __shared__ unsigned int pjs[8192];        // pre_j[b] bf16x2, 32 KB
  __shared__ unsigned int ent_s[4][128];
  __shared__ float pis[4][128];
  __shared__ float sred[8][128];
  __shared__ float s_s[4][128];
  __shared__ float r2[4][8][16];
  __shared__ int nn_s[4];
  int t = threadIdx.x;
  int node0 = blockIdx.x * 4;
  int b = blockIdx.x >> 5;
  const unsigned int* pjb = prejbf + b * 8192;
  for (int c = 0; c < 16; c++) pjs[c*512 + t] = pjb[c*512 + t];
  { int ii = t >> 7, f = t & 127;
    pis[ii][f] = pre_i[(node0 + ii)*128 + f] + be1[f];
    ent_s[ii][f] = ent[(node0 + ii)*128 + f]; }
  if (t < 4) nn_s[t] = cnt[node0 + t] & 0xffff;   // true neighbor count
  __syncthreads();
  int w = t >> 6, lane = t & 63;
  int ii = w >> 1, par = w & 1;
  float pia = pis[ii][2*lane];
  float pib = pis[ii][2*lane + 1];
  int nn = nn_s[ii];
  float a0 = 0.f, a1 = 0.f;
  for (int e = par; e < nn; e += 2) {
    unsigned int u = ent_s[ii][e];
    int j = u & 127;
    unsigned int hv = pjs[j*64 + lane];
    a0 += sspf(pia + bflo(hv));
    a1 += sspf(pib + bfhi(hv));
  }
  *(float2*)&sred[w][2*lane] = make_float2(a0, a1);
  __syncthreads();
  { int i2 = t >> 7, f = t & 127;
    s_s[i2][f] = sred[2*i2][f] + sred[2*i2+1][f]; }
  __syncthreads();
  { int i2 = t >> 7, o = t & 15, seg = (t >> 4) & 7;
    float p = 0.f;
    for (int f = seg*16; f < seg*16 + 16; f++) p += s_s[i2][f] * We2[f*16 + o];
    r2[i2][seg][o] = p; }
  __syncthreads();
  if (t < 64) {
    int i2 = t >> 4, o = t & 15;
    float v = be2[o] * (float)nn_s[i2];
    for (int seg = 0; seg < 8; seg++) v += r2[i2][seg][o];
    out[(node0 + i2)*16 + o] = v;
  }
}

// ---------------------------------------------------------------------------
extern "C" void kernel_launch(void* const* d_in, const int* in_sizes, int n_in,
                              void* d_out, int out_size, void* d_ws, size_t ws_size,
                              hipStream_t stream) {
  const float* coords = (const float*)d_in[0];
  const int*   species= (const int*)  d_in[1];
  const float* emb    = (const float*)d_in[2];
  const float* Wc1    = (const float*)d_in[3];
  const float* bc1    = (const float*)d_in[4];
  const float* Wc2    = (const float*)d_in[5];
  const float* bc2    = (const float*)d_in[6];
  const float* Wu1    = (const float*)d_in[7];
  const float* bu1    = (const float*)d_in[8];
  const float* Wu2    = (const float*)d_in[9];
  const float* bu2    = (const float*)d_in[10];
  const float* Wp1    = (const float*)d_in[11];
  const float* bp1    = (const float*)d_in[12];
  const float* Wp2    = (const float*)d_in[13];
  const float* bp2    = (const float*)d_in[14];
  const float* Wei    = (const float*)d_in[15];
  const float* Wej    = (const float*)d_in[16];
  const float* be1    = (const float*)d_in[17];
  const float* We2    = (const float*)d_in[18];
  const float* be2    = (const float*)d_in[19];
  float* out = (float*)d_out;

  float* wsf = (float*)d_ws;
  unsigned int* tb16   = (unsigned int*)wsf;               //  262,208 uints (4097x64)
  float*        h_a    = wsf + 524416;                     //  262,144
  float*        h_b    = wsf + 786560;                     //  262,144
  float*        pre_i  = wsf + 1048704;                    //  262,144
  unsigned int* hbf_a  = (unsigned int*)(wsf + 1310848);   //  131,072
  unsigned int* hbf_b  = (unsigned int*)(wsf + 1441920);   //  131,072
  unsigned int* prejbf = (unsigned int*)(wsf + 1572992);   //  131,072
  unsigned int* ent    = (unsigned int*)(wsf + 1704064);   //  262,144
  int*          cnt    = (int*)(wsf + 1966208);            //  2,048
  (void)in_sizes; (void)n_in; (void)out_size; (void)ws_size;

  prep_kernel<<<1536, 256, 0, stream>>>(coords, Wc1, bc1, Wc2, bc2, tb16, ent, cnt);
  conv_t<true, false><<<512, 512, 0, stream>>>(
      nullptr, nullptr, h_b, hbf_b, species, emb, tb16, ent, cnt,
      Wu1, bu1, Wu2, bu2,
      nullptr, nullptr, nullptr, nullptr, nullptr, nullptr, nullptr, nullptr, nullptr);
  conv_t<false, false><<<512, 512, 0, stream>>>(
      h_b, hbf_b, h_a, hbf_a, species, emb, tb16, ent, cnt,
      Wu1, bu1, Wu2, bu2,
      nullptr, nullptr, nullptr, nullptr, nullptr, nullptr, nullptr, nullptr, nullptr);
  conv_t<false, true><<<512, 512, 0, stream>>>(
      h_a, hbf_a, nullptr, nullptr, species, emb, tb16, ent, cnt,
      Wu1, bu1, Wu2, bu2,
      Wp1, bp1, Wp2, bp2, Wei, Wej, pre_i, prejbf, out);
  edgepool_kernel<<<512, 512, 0, stream>>>(pre_i, prejbf, ent, cnt, be1, We2, be2,
                                           out + 16384);
}

// Round 7
// 56.575 us; speedup vs baseline: 1.3402x; 1.0091x over previous
//
#include <hip/hip_runtime.h>

// MPDNN SchNet-style MPNN, 5-dispatch pipeline.
// R2: cooperative grid.sync ~120us/barrier on gfx950 -> multi-dispatch chain.
// R6 (57.1us) anchor: bf16 table + 4-deep gather (-5.5 vs R5). R5: noise ±2.5us.
// R7 analysis: per-molecule mega-kernel rejected by issue arithmetic (16 blocks
// = 6% of chip -> ~47us floor). This round: single change, message gathers
// 8-deep (nbr pad x16) — same mechanism that won R5->R6.
//  - Wf(d) -> 4096-row bf16 lookup table (1 MB, L2/L3-resident)
//  - compact neighbor lists (d<6, ~23% dense), entry = j | (table_row<<7)
//  - h fp32 (residual) + producer-packed bf16 (message staging)
//  - conv1 reads emb[species] directly; conv3 fuses NodePool + pre_i/pre_j
//  - c_aniso.sum(j) pushed through @We2

#define LN2F 0.69314718055994531f

__device__ __forceinline__ float sspf(float x) {          // softplus(x) - ln2, stable
  float e = __expf(-fabsf(x));
  return fmaxf(x, 0.0f) + __logf(1.0f + e) - LN2F;
}
__device__ __forceinline__ unsigned int f2bf(float x) {   // fp32 -> bf16 bits (RNE)
  unsigned int u = __float_as_uint(x);
  return (u + 0x7fffu + ((u >> 16) & 1u)) >> 16;
}
__device__ __forceinline__ float bflo(unsigned int u) { return __uint_as_float(u << 16); }
__device__ __forceinline__ float bfhi(unsigned int u) { return __uint_as_float(u & 0xffff0000u); }

// ---------------------------------------------------------------------------
// prep: blocks [0,1024): neighbor lists (2 nodes/block), pad to x16
//       blocks [1024,1536): filter table, 8 d-samples/block (4-row batching),
//                           packed to bf16x2 (64 uints/row)
// ---------------------------------------------------------------------------
__global__ __launch_bounds__(256) void prep_kernel(
    const float* __restrict__ coords,
    const float* __restrict__ Wc1, const float* __restrict__ bc1,
    const float* __restrict__ Wc2, const float* __restrict__ bc2,
    unsigned int* __restrict__ tb16,
    unsigned int* __restrict__ ent, int* __restrict__ cnt) {
  int t = threadIdx.x;
  if (blockIdx.x < 1024) {
    __shared__ int wc[4];
    int node = blockIdx.x * 2 + (t >> 7);
    int j = t & 127;
    int b = node >> 7, i = node & 127;
    const float* cb = coords + (b << 7) * 3;
    float dx = cb[i*3+0] - cb[j*3+0];
    float dy = cb[i*3+1] - cb[j*3+1];
    float dz = cb[i*3+2] - cb[j*3+2];
    float d  = sqrtf(dx*dx + dy*dy + dz*dz);
    bool valid = (d < 6.0f) && (j != i);
    int k = 4096;                                   // 4096 = zero row (pad)
    if (valid) { k = (int)(d * (4096.0f/6.0f)); if (k > 4095) k = 4095; }
    unsigned long long bal = __ballot(valid);
    int lane = t & 63, w = t >> 6;
    if (lane == 0) wc[w] = (int)__popcll(bal);
    __syncthreads();
    int ii = t >> 7;
    int nn = wc[2*ii] + wc[2*ii+1];
    int base = ((w & 1) ? wc[w-1] : 0) + (int)__popcll(bal & ((1ull << lane) - 1ull));
    if (valid) ent[node*128 + base] = (unsigned int)(j | (k << 7));
    int nnp = (nn + 15) & ~15;                      // pad to x16 for 8-deep gather
    if (nnp > 128) nnp = 128;                       // nn<=127 -> ok
    if (j >= nn && j < nnp) ent[node*128 + j] = (4096u << 7);
    if (j == 0) cnt[node] = nn | (nnp << 16);
  } else {
    __shared__ float rbf[8][32];
    __shared__ float hid[8][128];
    int tb = (int)blockIdx.x - 1024;                // 0..511
    int t0 = tb * 8;
    { int tt = t >> 5, kk = t & 31;                 // 256 threads = 8x32 exactly
      float d = (float)(t0 + tt) * (6.0f/4096.0f) + 0.5f * (6.0f/4096.0f);
      float mu = 0.5f + (float)kk * (5.5f/31.0f);
      float z = d - mu;
      rbf[tt][kk] = __expf(-8.0f * z * z); }        // 1/(2*0.25^2)=8
    __syncthreads();
    int f = t & 127, sub = t >> 7;                  // sub in 0..1 -> rows sub*4..+3
    float s0 = bc1[f], s1 = s0, s2 = s0, s3 = s0;
    int r0 = sub * 4;
    for (int kk = 0; kk < 32; kk++) {
      float wv = Wc1[kk*128 + f];
      s0 += rbf[r0+0][kk]*wv; s1 += rbf[r0+1][kk]*wv;
      s2 += rbf[r0+2][kk]*wv; s3 += rbf[r0+3][kk]*wv;
    }
    hid[r0+0][f] = sspf(s0); hid[r0+1][f] = sspf(s1);
    hid[r0+2][f] = sspf(s2); hid[r0+3][f] = sspf(s3);
    __syncthreads();
    float o0 = bc2[f], o1 = o0, o2 = o0, o3 = o0;
    for (int g = 0; g < 128; g++) {
      float wv = Wc2[g*128 + f];
      o0 += hid[r0+0][g]*wv; o1 += hid[r0+1][g]*wv;
      o2 += hid[r0+2][g]*wv; o3 += hid[r0+3][g]*wv;
    }
    // pack pairs of columns to bf16x2 (even f writes word f>>1)
    unsigned int l0 = f2bf(o0), l1 = f2bf(o1), l2 = f2bf(o2), l3 = f2bf(o3);
    unsigned int p0 = (unsigned int)__shfl_xor((int)l0, 1);
    unsigned int p1 = (unsigned int)__shfl_xor((int)l1, 1);
    unsigned int p2 = (unsigned int)__shfl_xor((int)l2, 1);
    unsigned int p3 = (unsigned int)__shfl_xor((int)l3, 1);
    if ((f & 1) == 0) {
      int fw = f >> 1;
      tb16[(t0+r0+0)*64 + fw] = l0 | (p0 << 16);
      tb16[(t0+r0+1)*64 + fw] = l1 | (p1 << 16);
      tb16[(t0+r0+2)*64 + fw] = l2 | (p2 << 16);
      tb16[(t0+r0+3)*64 + fw] = l3 | (p3 << 16);
    }
    if (tb == 0 && t < 64) tb16[4096*64 + t] = 0u;  // zero pad row
  }
}

// ---------------------------------------------------------------------------
// conv: one block = 4 nodes. message (bf16-table gather, 8 in flight) + update net.
// SRC_EMB: h_in is emb[species] computed on the fly (conv 1).
// LAST:    skip h stores; fuse NodePool (c_iso) + pre_i/pre_j (conv 3).
// ---------------------------------------------------------------------------
template<bool SRC_EMB, bool LAST>
__global__ __launch_bounds__(512) void conv_t(
    const float* __restrict__ h_in, const unsigned int* __restrict__ hbf_in,
    float* __restrict__ h_out, unsigned int* __restrict__ hbf_out,
    const int* __restrict__ species, const float* __restrict__ emb,
    const unsigned int* __restrict__ tb16, const unsigned int* __restrict__ ent,
    const int* __restrict__ cnt,
    const float* __restrict__ Wu1, const float* __restrict__ bu1,
    const float* __restrict__ Wu2, const float* __restrict__ bu2,
    const float* __restrict__ Wp1, const float* __restrict__ bp1,
    const float* __restrict__ Wp2, const float* __restrict__ bp2,
    const float* __restrict__ Wei, const float* __restrict__ Wej,
    float* __restrict__ pre_i, unsigned int* __restrict__ prejbf,
    float* __restrict__ out) {
  __shared__ unsigned int hsh[8192];        // h[b] as bf16x2, 32 KB
  __shared__ unsigned int ent_s[4][128];
  __shared__ float mred[8][128];
  __shared__ float m_s[4][128];
  __shared__ float red[4][4][128];
  __shared__ float u1_s[4][128];
  __shared__ int nn_s[4];
  int t = threadIdx.x;
  int node0 = blockIdx.x * 4;
  int b = blockIdx.x >> 5;

  if constexpr (SRC_EMB) {
    const int* spb = species + (b << 7);
    for (int c = 0; c < 16; c++) {
      int idx = c*512 + t;
      int j = idx >> 6, f2 = idx & 63;
      float2 v = *(const float2*)(emb + spb[j]*128 + 2*f2);
      hsh[idx] = (f2bf(v.y) << 16) | f2bf(v.x);
    }
  } else {
    const unsigned int* hb = hbf_in + b * 8192;
    for (int c = 0; c < 16; c++) hsh[c*512 + t] = hb[c*512 + t];
  }
  { int ii = t >> 7, f = t & 127;
    ent_s[ii][f] = ent[(node0 + ii)*128 + f]; }
  if (t < 4) nn_s[t] = cnt[node0 + t];
  __syncthreads();

  // --- message: wave pair by parity, 8 gathers in flight ---
  int w = t >> 6, lane = t & 63;
  int ii = w >> 1, par = w & 1;
  int nnp = nn_s[ii] >> 16;                 // padded count (multiple of 16)
  float a0 = 0.f, a1 = 0.f, b0 = 0.f, b1 = 0.f;
  float c0 = 0.f, c1 = 0.f, d0 = 0.f, d1 = 0.f;
  for (int e = par; e < nnp; e += 16) {
    unsigned int u0 = ent_s[ii][e],      u1 = ent_s[ii][e + 2];
    unsigned int u2 = ent_s[ii][e + 4],  u3 = ent_s[ii][e + 6];
    unsigned int u4 = ent_s[ii][e + 8],  u5 = ent_s[ii][e + 10];
    unsigned int u6 = ent_s[ii][e + 12], u7 = ent_s[ii][e + 14];
    unsigned int t0 = tb16[(u0 >> 7)*64 + lane];
    unsigned int t1 = tb16[(u1 >> 7)*64 + lane];
    unsigned int t2 = tb16[(u2 >> 7)*64 + lane];
    unsigned int t3 = tb16[(u3 >> 7)*64 + lane];
    unsigned int t4 = tb16[(u4 >> 7)*64 + lane];
    unsigned int t5 = tb16[(u5 >> 7)*64 + lane];
    unsigned int t6 = tb16[(u6 >> 7)*64 + lane];
    unsigned int t7 = tb16[(u7 >> 7)*64 + lane];
    unsigned int h0 = hsh[(u0 & 127)*64 + lane];
    unsigned int h1 = hsh[(u1 & 127)*64 + lane];
    unsigned int h2 = hsh[(u2 & 127)*64 + lane];
    unsigned int h3 = hsh[(u3 & 127)*64 + lane];
    unsigned int h4 = hsh[(u4 & 127)*64 + lane];
    unsigned int h5 = hsh[(u5 & 127)*64 + lane];
    unsigned int h6 = hsh[(u6 & 127)*64 + lane];
    unsigned int h7 = hsh[(u7 & 127)*64 + lane];
    a0 += bflo(t0) * bflo(h0); a1 += bfhi(t0) * bfhi(h0);
    b0 += bflo(t1) * bflo(h1); b1 += bfhi(t1) * bfhi(h1);
    c0 += bflo(t2) * bflo(h2); c1 += bfhi(t2) * bfhi(h2);
    d0 += bflo(t3) * bflo(h3); d1 += bfhi(t3) * bfhi(h3);
    a0 += bflo(t4) * bflo(h4); a1 += bfhi(t4) * bfhi(h4);
    b0 += bflo(t5) * bflo(h5); b1 += bfhi(t5) * bfhi(h5);
    c0 += bflo(t6) * bflo(h6); c1 += bfhi(t6) * bfhi(h6);
    d0 += bflo(t7) * bflo(h7); d1 += bfhi(t7) * bfhi(h7);
  }
  a0 += b0 + c0 + d0; a1 += b1 + c1 + d1;
  *(float2*)&mred[w][2*lane] = make_float2(a0, a1);
  __syncthreads();
  { int i2 = t >> 7, f = t & 127;
    m_s[i2][f] = mred[2*i2][f] + mred[2*i2+1][f]; }
  __syncthreads();

  // --- update net, 4 rows batched per weight load ---
  int g = t & 127, q = t >> 7;
  {
    float p0=0,p1=0,p2=0,p3=0;
    for (int f = q*32; f < q*32 + 32; f++) {
      float wv = Wu1[f*128 + g];
      p0 += m_s[0][f]*wv; p1 += m_s[1][f]*wv; p2 += m_s[2][f]*wv; p3 += m_s[3][f]*wv;
    }
    red[q][0][g]=p0; red[q][1][g]=p1; red[q][2][g]=p2; red[q][3][g]=p3;
  }
  __syncthreads();
  { int i2 = t >> 7, gg = t & 127;
    u1_s[i2][gg] = sspf(red[0][i2][gg]+red[1][i2][gg]+red[2][i2][gg]+red[3][i2][gg] + bu1[gg]); }
  __syncthreads();
  {
    float p0=0,p1=0,p2=0,p3=0;
    for (int f = q*32; f < q*32 + 32; f++) {
      float wv = Wu2[f*128 + g];
      p0 += u1_s[0][f]*wv; p1 += u1_s[1][f]*wv; p2 += u1_s[2][f]*wv; p3 += u1_s[3][f]*wv;
    }
    red[q][0][g]=p0; red[q][1][g]=p1; red[q][2][g]=p2; red[q][3][g]=p3;
  }
  __syncthreads();
  { int i2 = t >> 7, o = t & 127;
    int node = node0 + i2;
    float delta = red[0][i2][o]+red[1][i2][o]+red[2][i2][o]+red[3][i2][o] + bu2[o];
    float base;
    if constexpr (SRC_EMB) base = emb[species[node]*128 + o];
    else                   base = h_in[node*128 + o];
    float hf = base + delta;
    if constexpr (!LAST) {
      h_out[node*128 + o] = hf;
      unsigned int lo = f2bf(hf);
      unsigned int hi = (unsigned int)__shfl_xor((int)lo, 1);
      if ((o & 1) == 0) hbf_out[node*64 + (o >> 1)] = lo | (hi << 16);
    } else {
      u1_s[i2][o] = hf;                     // u1 dead here; keep h for pools
    }
  }
  if constexpr (LAST) {
    __syncthreads();
    float (*hs)[128]     = u1_s;
    float (*redp)[4][64] = reinterpret_cast<float (*)[4][64]>(red);
    float (*us)[64]      = reinterpret_cast<float (*)[64]>(m_s);
    int gp = t & 63, qp = t >> 6;           // qp 0..7 -> 16-wide f segment
    float p0=0,p1=0,p2=0,p3=0;
    for (int f = qp*16; f < qp*16 + 16; f++) {
      float wv = Wp1[f*64 + gp];
      p0 += hs[0][f]*wv; p1 += hs[1][f]*wv; p2 += hs[2][f]*wv; p3 += hs[3][f]*wv;
    }
    redp[qp][0][gp]=p0; redp[qp][1][gp]=p1; redp[qp][2][gp]=p2; redp[qp][3][gp]=p3;
    __syncthreads();
    if (t < 256) {
      int i4 = t >> 6, gg = t & 63;
      float s = bp1[gg];
      for (int q2 = 0; q2 < 8; q2++) s += redp[q2][i4][gg];
      us[i4][gg] = sspf(s);
    }
    __syncthreads();
    if (t < 32) {
      int i4 = t >> 3, o = t & 7;
      float v = bp2[o];
      for (int gg = 0; gg < 64; gg++) v += us[i4][gg] * Wp2[gg*8 + o];
      out[(node0 + i4)*8 + o] = v;
    }
    int o = t & 127, sel = (t >> 7) & 1, duo = t >> 8;
    const float* W = sel ? Wej : Wei;
    float q0 = 0.f, q1 = 0.f;
    for (int f = 0; f < 128; f++) {
      float wv = W[f*128 + o];
      q0 += hs[2*duo][f]*wv; q1 += hs[2*duo+1][f]*wv;
    }
    if (sel == 0) {
      pre_i[(node0 + 2*duo)*128 + o]     = q0;
      pre_i[(node0 + 2*duo + 1)*128 + o] = q1;
    } else {
      unsigned int l0 = f2bf(q0), l1 = f2bf(q1);
      unsigned int h0 = (unsigned int)__shfl_xor((int)l0, 1);
      unsigned int h1 = (unsigned int)__shfl_xor((int)l1, 1);
      if ((o & 1) == 0) {
        prejbf[(node0 + 2*duo)*64 + (o >> 1)]     = l0 | (h0 << 16);
        prejbf[(node0 + 2*duo + 1)*64 + (o >> 1)] = l1 | (h1 << 16);
      }
    }
  }
}

// ---------------------------------------------------------------------------
// edgepool: c_aniso_sum[node] = (sum_j ssp(pre_i+be1+pre_j)) @ We2 + be2*nn
// ---------------------------------------------------------------------------
__global__ __launch_bounds__(512) void edgepool_kernel(
    const float* __restrict__ pre_i, const unsigned int* __restrict__ prejbf,
    const unsigned int* __restrict__ ent, const int* __restrict__ cnt,
    const float* __restrict__ be1, const float* __restrict__ We2,
    const float* __restrict__ be2, float* __restrict__ out) {
  __shared__ unsigned int pjs[8192];        // pre_j[b] bf16x2, 32 KB
  __shared__ unsigned int ent_s[4][128];
  __shared__ float pis[4][128];
  __shared__ float sred[8][128];
  __shared__ float s_s[4][128];
  __shared__ float r2[4][8][16];
  __shared__ int nn_s[4];
  int t = threadIdx.x;
  int node0 = blockIdx.x * 4;
  int b = blockIdx.x >> 5;
  const unsigned int* pjb = prejbf + b * 8192;
  for (int c = 0; c < 16; c++) pjs[c*512 + t] = pjb[c*512 + t];
  { int ii = t >> 7, f = t & 127;
    pis[ii][f] = pre_i[(node0 + ii)*128 + f] + be1[f];
    ent_s[ii][f] = ent[(node0 + ii)*128 + f]; }
  if (t < 4) nn_s[t] = cnt[node0 + t] & 0xffff;   // true neighbor count
  __syncthreads();
  int w = t >> 6, lane = t & 63;
  int ii = w >> 1, par = w & 1;
  float pia = pis[ii][2*lane];
  float pib = pis[ii][2*lane + 1];
  int nn = nn_s[ii];
  float a0 = 0.f, a1 = 0.f;
  for (int e = par; e < nn; e += 2) {
    unsigned int u = ent_s[ii][e];
    int j = u & 127;
    unsigned int hv = pjs[j*64 + lane];
    a0 += sspf(pia + bflo(hv));
    a1 += sspf(pib + bfhi(hv));
  }
  *(float2*)&sred[w][2*lane] = make_float2(a0, a1);
  __syncthreads();
  { int i2 = t >> 7, f = t & 127;
    s_s[i2][f] = sred[2*i2][f] + sred[2*i2+1][f]; }
  __syncthreads();
  { int i2 = t >> 7, o = t & 15, seg = (t >> 4) & 7;
    float p = 0.f;
    for (int f = seg*16; f < seg*16 + 16; f++) p += s_s[i2][f] * We2[f*16 + o];
    r2[i2][seg][o] = p; }
  __syncthreads();
  if (t < 64) {
    int i2 = t >> 4, o = t & 15;
    float v = be2[o] * (float)nn_s[i2];
    for (int seg = 0; seg < 8; seg++) v += r2[i2][seg][o];
    out[(node0 + i2)*16 + o] = v;
  }
}

// ---------------------------------------------------------------------------
extern "C" void kernel_launch(void* const* d_in, const int* in_sizes, int n_in,
                              void* d_out, int out_size, void* d_ws, size_t ws_size,
                              hipStream_t stream) {
  const float* coords = (const float*)d_in[0];
  const int*   species= (const int*)  d_in[1];
  const float* emb    = (const float*)d_in[2];
  const float* Wc1    = (const float*)d_in[3];
  const float* bc1    = (const float*)d_in[4];
  const float* Wc2    = (const float*)d_in[5];
  const float* bc2    = (const float*)d_in[6];
  const float* Wu1    = (const float*)d_in[7];
  const float* bu1    = (const float*)d_in[8];
  const float* Wu2    = (const float*)d_in[9];
  const float* bu2    = (const float*)d_in[10];
  const float* Wp1    = (const float*)d_in[11];
  const float* bp1    = (const float*)d_in[12];
  const float* Wp2    = (const float*)d_in[13];
  const float* bp2    = (const float*)d_in[14];
  const float* Wei    = (const float*)d_in[15];
  const float* Wej    = (const float*)d_in[16];
  const float* be1    = (const float*)d_in[17];
  const float* We2    = (const float*)d_in[18];
  const float* be2    = (const float*)d_in[19];
  float* out = (float*)d_out;

  float* wsf = (float*)d_ws;
  unsigned int* tb16   = (unsigned int*)wsf;               //  262,208 uints (4097x64)
  float*        h_a    = wsf + 524416;                     //  262,144
  float*        h_b    = wsf + 786560;                     //  262,144
  float*        pre_i  = wsf + 1048704;                    //  262,144
  unsigned int* hbf_a  = (unsigned int*)(wsf + 1310848);   //  131,072
  unsigned int* hbf_b  = (unsigned int*)(wsf + 1441920);   //  131,072
  unsigned int* prejbf = (unsigned int*)(wsf + 1572992);   //  131,072
  unsigned int* ent    = (unsigned int*)(wsf + 1704064);   //  262,144
  int*          cnt    = (int*)(wsf + 1966208);            //  2,048
  (void)in_sizes; (void)n_in; (void)out_size; (void)ws_size;

  prep_kernel<<<1536, 256, 0, stream>>>(coords, Wc1, bc1, Wc2, bc2, tb16, ent, cnt);
  conv_t<true, false><<<512, 512, 0, stream>>>(
      nullptr, nullptr, h_b, hbf_b, species, emb, tb16, ent, cnt,
      Wu1, bu1, Wu2, bu2,
      nullptr, nullptr, nullptr, nullptr, nullptr, nullptr, nullptr, nullptr, nullptr);
  conv_t<false, false><<<512, 512, 0, stream>>>(
      h_b, hbf_b, h_a, hbf_a, species, emb, tb16, ent, cnt,
      Wu1, bu1, Wu2, bu2,
      nullptr, nullptr, nullptr, nullptr, nullptr, nullptr, nullptr, nullptr, nullptr);
  conv_t<false, true><<<512, 512, 0, stream>>>(
      h_a, hbf_a, nullptr, nullptr, species, emb, tb16, ent, cnt,
      Wu1, bu1, Wu2, bu2,
      Wp1, bp1, Wp2, bp2, Wei, Wej, pre_i, prejbf, out);
  edgepool_kernel<<<512, 512, 0, stream>>>(pre_i, prejbf, ent, cnt, be1, We2, be2,
                                           out + 16384);
}

// Round 8
// 53.206 us; speedup vs baseline: 1.4251x; 1.0633x over previous
//
#include <hip/hip_runtime.h>

// MPDNN SchNet-style MPNN, 5-dispatch pipeline.
// R2: cooperative grid.sync ~120us/barrier on gfx950 -> multi-dispatch chain.
// R7 (56.6us) anchor. 8-deep gather null -> message latency exhausted; pivot
// to locality/structure. R8: (1) XCD-affinity block swizzle (batch b -> XCD b/2)
// on all kernels so producer/consumer share an L2; (2) conv/edgepool gather h /
// pre_j rows directly from L2 (no 32KB LDS staging, fewer bytes, one less
// barrier); (3) prep materializes h_a/hbf_a (uniform convs). 2-node/256-thread
// blocks REJECTED by arithmetic: doubles Wu L2 traffic (+1.8us/conv).
//  - Wf(d) -> 4096-row bf16 lookup table (1 MB, per-XCD L2 copy)
//  - compact neighbor lists (d<6, ~23% dense), entry = j | (table_row<<7)
//  - h fp32 (residual) + producer-packed bf16 (message gathers)
//  - conv3 fuses NodePool + pre_i/pre_j; c_aniso.sum(j) pushed through @We2

#define LN2F 0.69314718055994531f

__device__ __forceinline__ float sspf(float x) {          // softplus(x) - ln2, stable
  float e = __expf(-fabsf(x));
  return fmaxf(x, 0.0f) + __logf(1.0f + e) - LN2F;
}
__device__ __forceinline__ unsigned int f2bf(float x) {   // fp32 -> bf16 bits (RNE)
  unsigned int u = __float_as_uint(x);
  return (u + 0x7fffu + ((u >> 16) & 1u)) >> 16;
}
__device__ __forceinline__ float bflo(unsigned int u) { return __uint_as_float(u << 16); }
__device__ __forceinline__ float bfhi(unsigned int u) { return __uint_as_float(u & 0xffff0000u); }

// ---------------------------------------------------------------------------
// prep: blocks [0,1024): neighbor lists + h/hbf materialize (2 nodes/block),
//       swizzled so batch b lands on XCD b/2. Pad lists to x16.
//       blocks [1024,1536): filter table, 8 d-samples/block, bf16x2-packed.
// ---------------------------------------------------------------------------
__global__ __launch_bounds__(256) void prep_kernel(
    const float* __restrict__ coords, const int* __restrict__ species,
    const float* __restrict__ emb,
    const float* __restrict__ Wc1, const float* __restrict__ bc1,
    const float* __restrict__ Wc2, const float* __restrict__ bc2,
    unsigned int* __restrict__ tb16, float* __restrict__ h_a,
    unsigned int* __restrict__ hbf_a,
    unsigned int* __restrict__ ent, int* __restrict__ cnt) {
  int t = threadIdx.x;
  if (blockIdx.x < 1024) {
    __shared__ int wc[4];
    int blk = (int)blockIdx.x;
    int Lb = ((blk & 7) << 7) | (blk >> 3);         // XCD-affinity swizzle (1024)
    int node = Lb * 2 + (t >> 7);
    int j = t & 127;
    int b = node >> 7, i = node & 127;
    const float* cb = coords + (b << 7) * 3;
    float dx = cb[i*3+0] - cb[j*3+0];
    float dy = cb[i*3+1] - cb[j*3+1];
    float dz = cb[i*3+2] - cb[j*3+2];
    float d  = sqrtf(dx*dx + dy*dy + dz*dz);
    bool valid = (d < 6.0f) && (j != i);
    int k = 4096;                                   // 4096 = zero table row (pad)
    if (valid) { k = (int)(d * (4096.0f/6.0f)); if (k > 4095) k = 4095; }
    unsigned long long bal = __ballot(valid);
    int lane = t & 63, w = t >> 6;
    if (lane == 0) wc[w] = (int)__popcll(bal);
    __syncthreads();
    int ii = t >> 7;
    int nn = wc[2*ii] + wc[2*ii+1];
    int base = ((w & 1) ? wc[w-1] : 0) + (int)__popcll(bal & ((1ull << lane) - 1ull));
    if (valid) ent[node*128 + base] = (unsigned int)(j | (k << 7));
    int nnp = (nn + 15) & ~15;                      // pad x16 (8-deep gather)
    if (nnp > 128) nnp = 128;
    if (j >= nn && j < nnp) ent[node*128 + j] = (4096u << 7);
    if (j == 0) cnt[node] = nn | (nnp << 16);
    // materialize h0 = emb[species]
    float hv = emb[species[node]*128 + j];
    h_a[node*128 + j] = hv;
    unsigned int lo = f2bf(hv);
    unsigned int hi = (unsigned int)__shfl_xor((int)lo, 1);
    if ((j & 1) == 0) hbf_a[node*64 + (j >> 1)] = lo | (hi << 16);
  } else {
    __shared__ float rbf[8][32];
    __shared__ float hid[8][128];
    int tb = (int)blockIdx.x - 1024;                // 0..511
    int t0 = tb * 8;
    { int tt = t >> 5, kk = t & 31;                 // 256 threads = 8x32 exactly
      float d = (float)(t0 + tt) * (6.0f/4096.0f) + 0.5f * (6.0f/4096.0f);
      float mu = 0.5f + (float)kk * (5.5f/31.0f);
      float z = d - mu;
      rbf[tt][kk] = __expf(-8.0f * z * z); }        // 1/(2*0.25^2)=8
    __syncthreads();
    int f = t & 127, sub = t >> 7;                  // sub in 0..1 -> rows sub*4..+3
    float s0 = bc1[f], s1 = s0, s2 = s0, s3 = s0;
    int r0 = sub * 4;
    for (int kk = 0; kk < 32; kk++) {
      float wv = Wc1[kk*128 + f];
      s0 += rbf[r0+0][kk]*wv; s1 += rbf[r0+1][kk]*wv;
      s2 += rbf[r0+2][kk]*wv; s3 += rbf[r0+3][kk]*wv;
    }
    hid[r0+0][f] = sspf(s0); hid[r0+1][f] = sspf(s1);
    hid[r0+2][f] = sspf(s2); hid[r0+3][f] = sspf(s3);
    __syncthreads();
    float o0 = bc2[f], o1 = o0, o2 = o0, o3 = o0;
    for (int g = 0; g < 128; g++) {
      float wv = Wc2[g*128 + f];
      o0 += hid[r0+0][g]*wv; o1 += hid[r0+1][g]*wv;
      o2 += hid[r0+2][g]*wv; o3 += hid[r0+3][g]*wv;
    }
    unsigned int l0 = f2bf(o0), l1 = f2bf(o1), l2 = f2bf(o2), l3 = f2bf(o3);
    unsigned int p0 = (unsigned int)__shfl_xor((int)l0, 1);
    unsigned int p1 = (unsigned int)__shfl_xor((int)l1, 1);
    unsigned int p2 = (unsigned int)__shfl_xor((int)l2, 1);
    unsigned int p3 = (unsigned int)__shfl_xor((int)l3, 1);
    if ((f & 1) == 0) {
      int fw = f >> 1;
      tb16[(t0+r0+0)*64 + fw] = l0 | (p0 << 16);
      tb16[(t0+r0+1)*64 + fw] = l1 | (p1 << 16);
      tb16[(t0+r0+2)*64 + fw] = l2 | (p2 << 16);
      tb16[(t0+r0+3)*64 + fw] = l3 | (p3 << 16);
    }
    if (tb == 0 && t < 64) tb16[4096*64 + t] = 0u;  // zero pad row
  }
}

// ---------------------------------------------------------------------------
// conv: one block = 4 nodes (swizzled). Direct L2 gather of table + hbf rows
// (8 in flight each), no LDS h-staging. Update net 4-rows-per-weight-load.
// LAST: skip h stores; fuse NodePool (c_iso) + pre_i/pre_j.
// ---------------------------------------------------------------------------
template<bool LAST>
__global__ __launch_bounds__(512) void conv_t(
    const float* __restrict__ h_in, const unsigned int* __restrict__ hbf_in,
    float* __restrict__ h_out, unsigned int* __restrict__ hbf_out,
    const unsigned int* __restrict__ tb16, const unsigned int* __restrict__ ent,
    const int* __restrict__ cnt,
    const float* __restrict__ Wu1, const float* __restrict__ bu1,
    const float* __restrict__ Wu2, const float* __restrict__ bu2,
    const float* __restrict__ Wp1, const float* __restrict__ bp1,
    const float* __restrict__ Wp2, const float* __restrict__ bp2,
    const float* __restrict__ Wei, const float* __restrict__ Wej,
    float* __restrict__ pre_i, unsigned int* __restrict__ prejbf,
    float* __restrict__ out) {
  __shared__ unsigned int ent_s[4][128];
  __shared__ float mred[8][128];
  __shared__ float m_s[4][128];
  __shared__ float red[4][4][128];
  __shared__ float u1_s[4][128];
  __shared__ int nn_s[4];
  int t = threadIdx.x;
  int blk = (int)blockIdx.x;
  int Lb = ((blk & 7) << 6) | (blk >> 3);   // XCD-affinity swizzle (512)
  int node0 = Lb * 4;
  int b = Lb >> 5;
  const unsigned int* hb = hbf_in + (b << 13);   // batch's bf16 h panel (L2)

  { int ii = t >> 7, f = t & 127;
    ent_s[ii][f] = ent[(node0 + ii)*128 + f]; }
  if (t < 4) nn_s[t] = cnt[node0 + t];
  __syncthreads();

  // --- message: wave pair by parity, 8 table + 8 h gathers in flight ---
  int w = t >> 6, lane = t & 63;
  int ii = w >> 1, par = w & 1;
  int nnp = nn_s[ii] >> 16;                 // padded count (multiple of 16)
  float a0 = 0.f, a1 = 0.f, b0 = 0.f, b1 = 0.f;
  float c0 = 0.f, c1 = 0.f, d0 = 0.f, d1 = 0.f;
  for (int e = par; e < nnp; e += 16) {
    unsigned int u0 = ent_s[ii][e],      u1 = ent_s[ii][e + 2];
    unsigned int u2 = ent_s[ii][e + 4],  u3 = ent_s[ii][e + 6];
    unsigned int u4 = ent_s[ii][e + 8],  u5 = ent_s[ii][e + 10];
    unsigned int u6 = ent_s[ii][e + 12], u7 = ent_s[ii][e + 14];
    unsigned int t0 = tb16[(u0 >> 7)*64 + lane];
    unsigned int t1 = tb16[(u1 >> 7)*64 + lane];
    unsigned int t2 = tb16[(u2 >> 7)*64 + lane];
    unsigned int t3 = tb16[(u3 >> 7)*64 + lane];
    unsigned int t4 = tb16[(u4 >> 7)*64 + lane];
    unsigned int t5 = tb16[(u5 >> 7)*64 + lane];
    unsigned int t6 = tb16[(u6 >> 7)*64 + lane];
    unsigned int t7 = tb16[(u7 >> 7)*64 + lane];
    unsigned int h0 = hb[(u0 & 127)*64 + lane];
    unsigned int h1 = hb[(u1 & 127)*64 + lane];
    unsigned int h2 = hb[(u2 & 127)*64 + lane];
    unsigned int h3 = hb[(u3 & 127)*64 + lane];
    unsigned int h4 = hb[(u4 & 127)*64 + lane];
    unsigned int h5 = hb[(u5 & 127)*64 + lane];
    unsigned int h6 = hb[(u6 & 127)*64 + lane];
    unsigned int h7 = hb[(u7 & 127)*64 + lane];
    a0 += bflo(t0) * bflo(h0); a1 += bfhi(t0) * bfhi(h0);
    b0 += bflo(t1) * bflo(h1); b1 += bfhi(t1) * bfhi(h1);
    c0 += bflo(t2) * bflo(h2); c1 += bfhi(t2) * bfhi(h2);
    d0 += bflo(t3) * bflo(h3); d1 += bfhi(t3) * bfhi(h3);
    a0 += bflo(t4) * bflo(h4); a1 += bfhi(t4) * bfhi(h4);
    b0 += bflo(t5) * bflo(h5); b1 += bfhi(t5) * bfhi(h5);
    c0 += bflo(t6) * bflo(h6); c1 += bfhi(t6) * bfhi(h6);
    d0 += bflo(t7) * bflo(h7); d1 += bfhi(t7) * bfhi(h7);
  }
  a0 += b0 + c0 + d0; a1 += b1 + c1 + d1;
  *(float2*)&mred[w][2*lane] = make_float2(a0, a1);
  __syncthreads();
  { int i2 = t >> 7, f = t & 127;
    m_s[i2][f] = mred[2*i2][f] + mred[2*i2+1][f]; }
  __syncthreads();

  // --- update net, 4 rows batched per weight load ---
  int g = t & 127, q = t >> 7;
  {
    float p0=0,p1=0,p2=0,p3=0;
    for (int f = q*32; f < q*32 + 32; f++) {
      float wv = Wu1[f*128 + g];
      p0 += m_s[0][f]*wv; p1 += m_s[1][f]*wv; p2 += m_s[2][f]*wv; p3 += m_s[3][f]*wv;
    }
    red[q][0][g]=p0; red[q][1][g]=p1; red[q][2][g]=p2; red[q][3][g]=p3;
  }
  __syncthreads();
  { int i2 = t >> 7, gg = t & 127;
    u1_s[i2][gg] = sspf(red[0][i2][gg]+red[1][i2][gg]+red[2][i2][gg]+red[3][i2][gg] + bu1[gg]); }
  __syncthreads();
  {
    float p0=0,p1=0,p2=0,p3=0;
    for (int f = q*32; f < q*32 + 32; f++) {
      float wv = Wu2[f*128 + g];
      p0 += u1_s[0][f]*wv; p1 += u1_s[1][f]*wv; p2 += u1_s[2][f]*wv; p3 += u1_s[3][f]*wv;
    }
    red[q][0][g]=p0; red[q][1][g]=p1; red[q][2][g]=p2; red[q][3][g]=p3;
  }
  __syncthreads();
  { int i2 = t >> 7, o = t & 127;
    int node = node0 + i2;
    float delta = red[0][i2][o]+red[1][i2][o]+red[2][i2][o]+red[3][i2][o] + bu2[o];
    float hf = h_in[node*128 + o] + delta;
    if constexpr (!LAST) {
      h_out[node*128 + o] = hf;
      unsigned int lo = f2bf(hf);
      unsigned int hi = (unsigned int)__shfl_xor((int)lo, 1);
      if ((o & 1) == 0) hbf_out[node*64 + (o >> 1)] = lo | (hi << 16);
    } else {
      u1_s[i2][o] = hf;                     // u1 dead here; keep h for pools
    }
  }
  if constexpr (LAST) {
    __syncthreads();
    float (*hs)[128]     = u1_s;
    float (*redp)[4][64] = reinterpret_cast<float (*)[4][64]>(red);
    float (*us)[64]      = reinterpret_cast<float (*)[64]>(m_s);
    int gp = t & 63, qp = t >> 6;           // qp 0..7 -> 16-wide f segment
    float p0=0,p1=0,p2=0,p3=0;
    for (int f = qp*16; f < qp*16 + 16; f++) {
      float wv = Wp1[f*64 + gp];
      p0 += hs[0][f]*wv; p1 += hs[1][f]*wv; p2 += hs[2][f]*wv; p3 += hs[3][f]*wv;
    }
    redp[qp][0][gp]=p0; redp[qp][1][gp]=p1; redp[qp][2][gp]=p2; redp[qp][3][gp]=p3;
    __syncthreads();
    if (t < 256) {
      int i4 = t >> 6, gg = t & 63;
      float s = bp1[gg];
      for (int q2 = 0; q2 < 8; q2++) s += redp[q2][i4][gg];
      us[i4][gg] = sspf(s);
    }
    __syncthreads();
    if (t < 32) {
      int i4 = t >> 3, o = t & 7;
      float v = bp2[o];
      for (int gg = 0; gg < 64; gg++) v += us[i4][gg] * Wp2[gg*8 + o];
      out[(node0 + i4)*8 + o] = v;
    }
    int o = t & 127, sel = (t >> 7) & 1, duo = t >> 8;
    const float* W = sel ? Wej : Wei;
    float q0 = 0.f, q1 = 0.f;
    for (int f = 0; f < 128; f++) {
      float wv = W[f*128 + o];
      q0 += hs[2*duo][f]*wv; q1 += hs[2*duo+1][f]*wv;
    }
    if (sel == 0) {
      pre_i[(node0 + 2*duo)*128 + o]     = q0;
      pre_i[(node0 + 2*duo + 1)*128 + o] = q1;
    } else {
      unsigned int l0 = f2bf(q0), l1 = f2bf(q1);
      unsigned int h0 = (unsigned int)__shfl_xor((int)l0, 1);
      unsigned int h1 = (unsigned int)__shfl_xor((int)l1, 1);
      if ((o & 1) == 0) {
        prejbf[(node0 + 2*duo)*64 + (o >> 1)]     = l0 | (h0 << 16);
        prejbf[(node0 + 2*duo + 1)*64 + (o >> 1)] = l1 | (h1 << 16);
      }
    }
  }
}

// ---------------------------------------------------------------------------
// edgepool: c_aniso_sum[node] = (sum_j ssp(pre_i+be1+pre_j)) @ We2 + be2*nn
// Direct L2 gather of pre_j rows, padded loop + exact pad-subtraction
// (pad entries alias j=0; subtract cp * ssp(pia + row0)).
// ---------------------------------------------------------------------------
__global__ __launch_bounds__(512) void edgepool_kernel(
    const float* __restrict__ pre_i, const unsigned int* __restrict__ prejbf,
    const unsigned int* __restrict__ ent, const int* __restrict__ cnt,
    const float* __restrict__ be1, const float* __restrict__ We2,
    const float* __restrict__ be2, float* __restrict__ out) {
  __shared__ unsigned int ent_s[4][128];
  __shared__ float pis[4][128];
  __shared__ float sred[8][128];
  __shared__ float s_s[4][128];
  __shared__ float r2[4][8][16];
  __shared__ int nn_s[4];
  int t = threadIdx.x;
  int blk = (int)blockIdx.x;
  int Lb = ((blk & 7) << 6) | (blk >> 3);   // XCD-affinity swizzle (512)
  int node0 = Lb * 4;
  int b = Lb >> 5;
  const unsigned int* pjb = prejbf + (b << 13);
  { int ii = t >> 7, f = t & 127;
    pis[ii][f] = pre_i[(node0 + ii)*128 + f] + be1[f];
    ent_s[ii][f] = ent[(node0 + ii)*128 + f]; }
  if (t < 4) nn_s[t] = cnt[node0 + t];
  __syncthreads();
  int w = t >> 6, lane = t & 63;
  int ii = w >> 1, par = w & 1;
  float pia = pis[ii][2*lane];
  float pib = pis[ii][2*lane + 1];
  int cw = nn_s[ii];
  int nn = cw & 0xffff, nnp = cw >> 16;
  float a0 = 0.f, a1 = 0.f;
  for (int e = par; e < nnp; e += 8) {
    unsigned int u0 = ent_s[ii][e],     u1 = ent_s[ii][e + 2];
    unsigned int u2 = ent_s[ii][e + 4], u3 = ent_s[ii][e + 6];
    unsigned int v0 = pjb[(u0 & 127)*64 + lane];
    unsigned int v1 = pjb[(u1 & 127)*64 + lane];
    unsigned int v2 = pjb[(u2 & 127)*64 + lane];
    unsigned int v3 = pjb[(u3 & 127)*64 + lane];
    a0 += sspf(pia + bflo(v0)) + sspf(pia + bflo(v1))
        + sspf(pia + bflo(v2)) + sspf(pia + bflo(v3));
    a1 += sspf(pib + bfhi(v0)) + sspf(pib + bfhi(v1))
        + sspf(pib + bfhi(v2)) + sspf(pib + bfhi(v3));
  }
  // exact pad correction: pads (e in [nn,nnp)) read row j=0
  int npad = nnp - nn;
  int cp = (npad >> 1) + (((npad & 1) != 0 && (nn & 1) == par) ? 1 : 0);
  if (cp > 0) {
    unsigned int v0 = pjb[lane];
    a0 -= (float)cp * sspf(pia + bflo(v0));
    a1 -= (float)cp * sspf(pib + bfhi(v0));
  }
  *(float2*)&sred[w][2*lane] = make_float2(a0, a1);
  __syncthreads();
  { int i2 = t >> 7, f = t & 127;
    s_s[i2][f] = sred[2*i2][f] + sred[2*i2+1][f]; }
  __syncthreads();
  { int i2 = t >> 7, o = t & 15, seg = (t >> 4) & 7;
    float p = 0.f;
    for (int f = seg*16; f < seg*16 + 16; f++) p += s_s[i2][f] * We2[f*16 + o];
    r2[i2][seg][o] = p; }
  __syncthreads();
  if (t < 64) {
    int i2 = t >> 4, o = t & 15;
    float v = be2[o] * (float)(nn_s[i2] & 0xffff);
    for (int seg = 0; seg < 8; seg++) v += r2[i2][seg][o];
    out[(node0 + i2)*16 + o] = v;
  }
}

// ---------------------------------------------------------------------------
extern "C" void kernel_launch(void* const* d_in, const int* in_sizes, int n_in,
                              void* d_out, int out_size, void* d_ws, size_t ws_size,
                              hipStream_t stream) {
  const float* coords = (const float*)d_in[0];
  const int*   species= (const int*)  d_in[1];
  const float* emb    = (const float*)d_in[2];
  const float* Wc1    = (const float*)d_in[3];
  const float* bc1    = (const float*)d_in[4];
  const float* Wc2    = (const float*)d_in[5];
  const float* bc2    = (const float*)d_in[6];
  const float* Wu1    = (const float*)d_in[7];
  const float* bu1    = (const float*)d_in[8];
  const float* Wu2    = (const float*)d_in[9];
  const float* bu2    = (const float*)d_in[10];
  const float* Wp1    = (const float*)d_in[11];
  const float* bp1    = (const float*)d_in[12];
  const float* Wp2    = (const float*)d_in[13];
  const float* bp2    = (const float*)d_in[14];
  const float* Wei    = (const float*)d_in[15];
  const float* Wej    = (const float*)d_in[16];
  const float* be1    = (const float*)d_in[17];
  const float* We2    = (const float*)d_in[18];
  const float* be2    = (const float*)d_in[19];
  float* out = (float*)d_out;

  float* wsf = (float*)d_ws;
  unsigned int* tb16   = (unsigned int*)wsf;               //  262,208 uints (4097x64)
  float*        h_a    = wsf + 524416;                     //  262,144
  float*        h_b    = wsf + 786560;                     //  262,144
  float*        pre_i  = wsf + 1048704;                    //  262,144
  unsigned int* hbf_a  = (unsigned int*)(wsf + 1310848);   //  131,072
  unsigned int* hbf_b  = (unsigned int*)(wsf + 1441920);   //  131,072
  unsigned int* prejbf = (unsigned int*)(wsf + 1572992);   //  131,072
  unsigned int* ent    = (unsigned int*)(wsf + 1704064);   //  262,144
  int*          cnt    = (int*)(wsf + 1966208);            //  2,048
  (void)in_sizes; (void)n_in; (void)out_size; (void)ws_size;

  prep_kernel<<<1536, 256, 0, stream>>>(coords, species, emb, Wc1, bc1, Wc2, bc2,
                                        tb16, h_a, hbf_a, ent, cnt);
  conv_t<false><<<512, 512, 0, stream>>>(
      h_a, hbf_a, h_b, hbf_b, tb16, ent, cnt,
      Wu1, bu1, Wu2, bu2,
      nullptr, nullptr, nullptr, nullptr, nullptr, nullptr, nullptr, nullptr, nullptr);
  conv_t<false><<<512, 512, 0, stream>>>(
      h_b, hbf_b, h_a, hbf_a, tb16, ent, cnt,
      Wu1, bu1, Wu2, bu2,
      nullptr, nullptr, nullptr, nullptr, nullptr, nullptr, nullptr, nullptr, nullptr);
  conv_t<true><<<512, 512, 0, stream>>>(
      h_a, hbf_a, nullptr, nullptr, tb16, ent, cnt,
      Wu1, bu1, Wu2, bu2,
      Wp1, bp1, Wp2, bp2, Wei, Wej, pre_i, prejbf, out);
  edgepool_kernel<<<512, 512, 0, stream>>>(pre_i, prejbf, ent, cnt, be1, We2, be2,
                                           out + 16384);
}